// Round 4
// baseline (5381.625 us; speedup 1.0000x reference)
//
#include <hip/hip_runtime.h>

// GCN decoder: 4 x (bucket-binned degree-norm aggregation + register-tiled fp32 GEMM).
// upsample2 identity: h = upsample2(x) @ W has h[2i]==h[2i+1] -> compute h on the
// pre-upsample node set, index with (node >> HSHIFT).
// Aggregation per layer:
//   out[d][c] = b[c] + dinv[d]*( dinv[d]*h[d>>s][c] + sum_{e:dst=d} dinv[src_e]*h[src_e>>s][c] )
// Edges are binned by dst-bucket (NPB nodes/bucket, 782 buckets per layer); a block owns a
// bucket, accumulates in LDS via ds_add_f32, writes out exactly once. Exact per-node degree
// is recovered from the binned edges (bucket_deg) -> no per-node random atomics anywhere.

static inline int cdiv(long a, int b) { return (int)((a + b - 1) / b); }

// ---------------- binning ----------------
template <int SHIFT>
__global__ void bin_count_kernel(const int* __restrict__ dst, int* __restrict__ cnt, int E) {
  int e = blockIdx.x * blockDim.x + threadIdx.x;
  if (e < E) atomicAdd(&cnt[dst[e] >> SHIFT], 1);  // 782 hot counters, fire-and-forget
}

// single block; nb <= 1023. offs/cur <- exclusive scan of cnt; offs[nb] = total.
__global__ __launch_bounds__(1024) void scan_offs_kernel(const int* __restrict__ cnt,
                                                         int* __restrict__ offs,
                                                         int* __restrict__ cur, int nb) {
  __shared__ int tmp[1024];
  int i = threadIdx.x;
  int v = (i < nb) ? cnt[i] : 0;
  tmp[i] = v;
  __syncthreads();
  for (int off = 1; off < 1024; off <<= 1) {
    int t = (i >= off) ? tmp[i - off] : 0;
    __syncthreads();
    tmp[i] += t;
    __syncthreads();
  }
  if (i <= nb) {
    int excl = tmp[i] - v;  // at i==nb: v==0 -> excl == grand total
    offs[i] = excl;
    cur[i] = excl;
  }
}

// bins[pos] = src | (dst_local << 18). Appends cluster at 782 bucket frontiers -> streamed.
template <int SHIFT>
__global__ void bin_fill_kernel(const int* __restrict__ src, const int* __restrict__ dst,
                                int* __restrict__ cur, int* __restrict__ bins, int E) {
  int e = blockIdx.x * blockDim.x + threadIdx.x;
  if (e < E) {
    int d = dst[e];
    int pos = atomicAdd(&cur[d >> SHIFT], 1);
    bins[pos] = src[e] | ((d & ((1 << SHIFT) - 1)) << 18);
  }
}

// exact per-node degree from binned edges (streamed reads, LDS histogram, coalesced dinv)
template <int NPB>
__global__ __launch_bounds__(256) void bucket_deg_kernel(const int* __restrict__ bins,
                                                         const int* __restrict__ offs,
                                                         float* __restrict__ dinv, int n) {
  __shared__ int scnt[NPB];
  const int bb = blockIdx.x;
  for (int i = threadIdx.x; i < NPB; i += 256) scnt[i] = 0;
  __syncthreads();
  const int start = offs[bb], end = offs[bb + 1];
  for (int e = start + (int)threadIdx.x; e < end; e += 256)
    atomicAdd(&scnt[bins[e] >> 18], 1);
  __syncthreads();
  for (int i = threadIdx.x; i < NPB; i += 256) {
    int node = bb * NPB + i;
    if (node < n) dinv[node] = rsqrtf((float)scnt[i] + 1.0f);  // +1 = self loop
  }
}

// ---------------- bucket gather ----------------
template <int C, int NPB, int HSHIFT>
__global__ __launch_bounds__(512) void bucket_gather_kernel(const int* __restrict__ bins,
                                                            const int* __restrict__ offs,
                                                            const float* __restrict__ dinv,
                                                            const float* __restrict__ h,
                                                            const float* __restrict__ b,
                                                            float* __restrict__ out, int n) {
  __shared__ float acc[NPB * C];
  const int tid = threadIdx.x;
  const int bb = blockIdx.x;
  const int nodebase = bb * NPB;
  // init with self-loop term
  for (int idx = tid; idx < NPB * C; idx += 512) {
    int node = nodebase + idx / C;
    int c = idx % C;
    float v = 0.f;
    if (node < n) v = dinv[node] * h[((long)(node >> HSHIFT)) * C + c];
    acc[idx] = v;
  }
  __syncthreads();
  const int start = offs[bb], end = offs[bb + 1];
  constexpr int LPE = (C < 64) ? C : 64;  // lanes cooperating on one edge
  constexpr int EPW = 64 / LPE;           // edges in flight per wave
  constexpr int VEC = (C + 63) / 64;      // channel chunks per lane (C >= 64)
  const int wave = tid >> 6;
  const int lane = tid & 63;
  const int sub = lane / LPE;
  const int c0 = lane % LPE;
  for (int e0 = start + wave * EPW; e0 < end; e0 += 8 * EPW) {
    int e = e0 + sub;
    if (e < end) {
      int p = bins[e];
      int s = p & 0x3FFFF;
      int dl = p >> 18;
      float w = dinv[s];
      long row = ((long)(s >> HSHIFT)) * C;
#pragma unroll
      for (int v = 0; v < VEC; v++) {
        int c = c0 + v * 64;
        atomicAdd(&acc[dl * C + c], w * h[row + c]);  // ds_add_f32, lane-consecutive banks
      }
    }
  }
  __syncthreads();
  for (int idx = tid; idx < NPB * C; idx += 512) {
    int node = nodebase + idx / C;
    if (node < n) {
      int c = idx % C;
      out[(long)node * C + c] = fmaf(dinv[node], acc[idx], b[c]);
    }
  }
}

// ---------------- GEMMs (unchanged from R3, proven correct) ----------------
template <int CIN, int COUT, bool RELU>
__global__ __launch_bounds__(256) void gemm_tiled(const float* __restrict__ x,
                                                  const float* __restrict__ W,
                                                  float* __restrict__ h, int n) {
  constexpr int TM = 32, KT = 32, TR = 4;
  constexpr int TC = COUT / 32;
  __shared__ float xs[TM][KT + 1];
  __shared__ float ws[KT][COUT];
  const int tid = threadIdx.x;
  const int cg = tid & 31;
  const int rg = tid >> 5;
  const int c0 = cg * TC;
  const int r0 = rg * TR;
  const int rowbase = blockIdx.x * TM;
  float acc[TR][TC];
#pragma unroll
  for (int i = 0; i < TR; i++)
#pragma unroll
    for (int j = 0; j < TC; j++) acc[i][j] = 0.f;

  for (int k0 = 0; k0 < CIN; k0 += KT) {
    __syncthreads();
#pragma unroll
    for (int t = 0; t < TM * KT / 256; t++) {
      int idx = tid + t * 256;
      int r = idx >> 5, k = idx & 31;
      int gr = rowbase + r;
      float v = 0.f;
      if (gr < n) {
        v = x[(long)gr * CIN + k0 + k];
        if (RELU) v = fmaxf(v, 0.f);
      }
      xs[r][k] = v;
    }
#pragma unroll
    for (int t = 0; t < KT * COUT / 256; t++) {
      int idx = tid + t * 256;
      int k = idx / COUT, c = idx % COUT;
      ws[k][c] = W[(long)(k0 + k) * COUT + c];
    }
    __syncthreads();
#pragma unroll 4
    for (int k = 0; k < KT; k++) {
      float a[TR], w[TC];
#pragma unroll
      for (int i = 0; i < TR; i++) a[i] = xs[r0 + i][k];
#pragma unroll
      for (int j = 0; j < TC; j++) w[j] = ws[k][c0 + j];
#pragma unroll
      for (int i = 0; i < TR; i++)
#pragma unroll
        for (int j = 0; j < TC; j++) acc[i][j] = fmaf(a[i], w[j], acc[i][j]);
    }
  }
#pragma unroll
  for (int i = 0; i < TR; i++) {
    int gr = rowbase + r0 + i;
    if (gr < n) {
#pragma unroll
      for (int j = 0; j < TC; j++) h[(long)gr * COUT + c0 + j] = acc[i][j];
    }
  }
}

template <int CIN, int COUT, int TM, bool RELU>
__global__ __launch_bounds__(256) void gemm_small(const float* __restrict__ x,
                                                  const float* __restrict__ W,
                                                  float* __restrict__ h, int n) {
  __shared__ float xs[TM][CIN + 1];
  const int tid = threadIdx.x;
  const int base = blockIdx.x * TM;
  for (int idx = tid; idx < TM * CIN; idx += 256) {
    int m = idx / CIN, k = idx - m * CIN;
    int r = base + m;
    float v = 0.f;
    if (r < n) {
      v = x[(long)r * CIN + k];
      if (RELU) v = fmaxf(v, 0.f);
    }
    xs[m][k] = v;
  }
  __syncthreads();
  constexpr int GROUPS = 256 / COUT;
  constexpr int ACC = TM / GROUPS;
  const int c = tid % COUT;
  const int mg = tid / COUT;
  float acc[ACC];
#pragma unroll
  for (int a = 0; a < ACC; a++) acc[a] = 0.f;
#pragma unroll 8
  for (int k = 0; k < CIN; k++) {
    float wk = W[k * COUT + c];
#pragma unroll
    for (int a = 0; a < ACC; a++) acc[a] = fmaf(xs[mg + a * GROUPS][k], wk, acc[a]);
  }
#pragma unroll
  for (int a = 0; a < ACC; a++) {
    int r = base + mg + a * GROUPS;
    if (r < n) h[(long)r * COUT + c] = acc[a];
  }
}

extern "C" void kernel_launch(void* const* d_in, const int* in_sizes, int n_in,
                              void* d_out, int out_size, void* d_ws, size_t ws_size,
                              hipStream_t stream) {
  const float* z  = (const float*)d_in[0];
  const int* ei   = (const int*)d_in[1];
  const int* ps2  = (const int*)d_in[2];
  const int* ps1  = (const int*)d_in[3];
  const int* ps0  = (const int*)d_in[4];
  const float* W1 = (const float*)d_in[5];  const float* b1 = (const float*)d_in[6];
  const float* W2 = (const float*)d_in[7];  const float* b2 = (const float*)d_in[8];
  const float* W3 = (const float*)d_in[9];  const float* b3 = (const float*)d_in[10];
  const float* W4 = (const float*)d_in[11]; const float* b4 = (const float*)d_in[12];
  float* out = (float*)d_out;

  const int N  = in_sizes[0] / 256;  // 25000
  const int E1 = in_sizes[1] / 2;    // 400000
  const int E2 = in_sizes[2] / 2;    // 800000
  const int E3 = in_sizes[3] / 2;    // 1600000
  const int E4 = in_sizes[4] / 2;    // 3200000
  const int n1 = N, n2 = 2 * N, n3 = 4 * N, n4 = 8 * N;
  // buckets: NPB per layer = 32/64/128/256 -> nb = 782 for all layers
  const int nb1 = cdiv(n1, 32), nb2 = cdiv(n2, 64), nb3 = cdiv(n3, 128), nb4 = cdiv(n4, 256);

  const long BUF = (long)N * 256;  // 6.4M floats per rotating buffer
  float* A  = (float*)d_ws;
  float* B  = A + BUF;
  float* Cb = B + BUF;

  // L1 aux in Cb base (dead before gemm2 writes h2 there)
  int*   cnt1  = (int*)Cb;
  int*   offs1 = cnt1 + 1024;
  int*   cur1  = offs1 + 1024;
  int*   bins1 = cur1 + 1024;           // E1 ints
  float* dinv1 = (float*)(bins1 + E1);  // n1 floats   (total ~428k floats << 3.2M)
  // L2 aux in Cb upper half (h2 = N*128 = 3.2M floats exactly fills lower half)
  int*   cnt2  = (int*)(Cb + BUF / 2);
  int*   offs2 = cnt2 + 1024;
  int*   cur2  = offs2 + 1024;
  int*   bins2 = cur2 + 1024;           // E2 ints
  float* dinv2 = (float*)(bins2 + E2);  // n2 floats   (~853k floats <= 3.2M)
  // L3 aux in B upper half (out1 dead after gemm2; h3 = 3.2M floats in B lower)
  int*   cnt3  = (int*)(B + BUF / 2);
  int*   offs3 = cnt3 + 1024;
  int*   cur3  = offs3 + 1024;
  int*   bins3 = cur3 + 1024;           // E3 ints
  float* dinv3 = (float*)(bins3 + E3);  // n3 floats   (~1.70M <= 3.2M)
  // L4 aux in B base (all of B dead after gather3)
  int*   cnt4  = (int*)B;
  int*   offs4 = cnt4 + 1024;
  int*   cur4  = offs4 + 1024;
  int*   bins4 = cur4 + 1024;           // E4 ints
  float* dinv4 = (float*)(bins4 + E4);  // n4 floats   (~3.40M <= 6.4M)

  // ---------------- Layer 1: h1=A (Nx256), out1=B ----------------
  hipMemsetAsync(cnt1, 0, 4096, stream);
  bin_count_kernel<5><<<cdiv(E1, 256), 256, 0, stream>>>(ei + E1, cnt1, E1);
  scan_offs_kernel<<<1, 1024, 0, stream>>>(cnt1, offs1, cur1, nb1);
  bin_fill_kernel<5><<<cdiv(E1, 256), 256, 0, stream>>>(ei, ei + E1, cur1, bins1, E1);
  bucket_deg_kernel<32><<<nb1, 256, 0, stream>>>(bins1, offs1, dinv1, n1);
  gemm_tiled<256, 256, false><<<cdiv(n1, 32), 256, 0, stream>>>(z, W1, A, n1);
  bucket_gather_kernel<256, 32, 0><<<nb1, 512, 0, stream>>>(bins1, offs1, dinv1, A, b1, B, n1);

  // ---------------- Layer 2: h2=Cb lower (Nx128), out2=A (2N x 128) ----------------
  hipMemsetAsync(cnt2, 0, 4096, stream);
  bin_count_kernel<6><<<cdiv(E2, 256), 256, 0, stream>>>(ps2 + E2, cnt2, E2);
  scan_offs_kernel<<<1, 1024, 0, stream>>>(cnt2, offs2, cur2, nb2);
  bin_fill_kernel<6><<<cdiv(E2, 256), 256, 0, stream>>>(ps2, ps2 + E2, cur2, bins2, E2);
  bucket_deg_kernel<64><<<nb2, 256, 0, stream>>>(bins2, offs2, dinv2, n2);
  gemm_tiled<256, 128, true><<<cdiv(N, 32), 256, 0, stream>>>(B, W2, Cb, N);
  bucket_gather_kernel<128, 64, 1><<<nb2, 512, 0, stream>>>(bins2, offs2, dinv2, Cb, b2, A, n2);

  // ---------------- Layer 3: h3=B lower (2N x 64), out3=Cb (4N x 64) ----------------
  hipMemsetAsync(cnt3, 0, 4096, stream);
  bin_count_kernel<7><<<cdiv(E3, 256), 256, 0, stream>>>(ps1 + E3, cnt3, E3);
  scan_offs_kernel<<<1, 1024, 0, stream>>>(cnt3, offs3, cur3, nb3);
  bin_fill_kernel<7><<<cdiv(E3, 256), 256, 0, stream>>>(ps1, ps1 + E3, cur3, bins3, E3);
  bucket_deg_kernel<128><<<nb3, 256, 0, stream>>>(bins3, offs3, dinv3, n3);
  gemm_tiled<128, 64, true><<<cdiv(2 * N, 32), 256, 0, stream>>>(A, W3, B, 2 * N);
  bucket_gather_kernel<64, 128, 1><<<nb3, 512, 0, stream>>>(bins3, offs3, dinv3, B, b3, Cb, n3);

  // ---------------- Layer 4: h4=A base (4N x 8), out4=d_out (8N x 8) ----------------
  hipMemsetAsync(cnt4, 0, 4096, stream);
  bin_count_kernel<8><<<cdiv(E4, 256), 256, 0, stream>>>(ps0 + E4, cnt4, E4);
  scan_offs_kernel<<<1, 1024, 0, stream>>>(cnt4, offs4, cur4, nb4);
  bin_fill_kernel<8><<<cdiv(E4, 256), 256, 0, stream>>>(ps0, ps0 + E4, cur4, bins4, E4);
  bucket_deg_kernel<256><<<nb4, 256, 0, stream>>>(bins4, offs4, dinv4, n4);
  gemm_small<64, 8, 32, true><<<cdiv(4 * N, 32), 256, 0, stream>>>(Cb, W4, A, 4 * N);
  bucket_gather_kernel<8, 256, 1><<<nb4, 512, 0, stream>>>(bins4, offs4, dinv4, A, b4, out, n4);
}

// Round 5
// 2776.733 us; speedup vs baseline: 1.9381x; 1.9381x over previous
//
#include <hip/hip_runtime.h>

// GCN decoder: 4 x (radix-partitioned bucket aggregation + register-tiled fp32 GEMM).
// upsample2 identity: h = upsample2(x) @ W has h[2i]==h[2i+1] -> compute h on the
// pre-upsample node set, index with (node >> HSHIFT).
// Aggregation: out[d][c] = b[c] + dinv[d]*( dinv[d]*h[d>>s][c] + sum_{e:dst=d} dinv[src]*h[src>>s][c] )
// Edges partitioned by dst-bucket (NPB nodes/bucket, NB=782 buckets) with a DETERMINISTIC
// two-pass radix partition: per-block LDS histograms -> global scan -> LDS-cursor scatter.
// No global atomics anywhere (R4's 782 hot global cursors were contention-bound: 748us/fill).

static inline int cdiv(long a, int b) { return (int)((a + b - 1) / b); }

static constexpr int NBLK = 256;  // partition blocks; appends/(block,bucket) stay clustered

// ---------------- partition pass 1: per-block histogram (transposed write) ----------------
template <int SHIFT>
__global__ __launch_bounds__(256) void part_hist_kernel(const int* __restrict__ dst,
                                                        int* __restrict__ histG,
                                                        int E, int chunk, int NB) {
  __shared__ int hist[1024];
  for (int i = threadIdx.x; i < NB; i += 256) hist[i] = 0;
  __syncthreads();
  const int k = blockIdx.x;
  const int lo = k * chunk, hi = min(E, lo + chunk);
  for (int e = lo + (int)threadIdx.x; e < hi; e += 256)
    atomicAdd(&hist[dst[e] >> SHIFT], 1);  // LDS atomic, block-private
  __syncthreads();
  for (int i = threadIdx.x; i < NB; i += 256)
    histG[i * NBLK + k] = hist[i];  // bucket-major for the scan
}

// ---------------- 3-kernel exclusive scan (in-place safe) ----------------
__global__ void scan_block_kernel(const int* __restrict__ in, int* __restrict__ outv,
                                  int* __restrict__ psum, int n) {
  __shared__ int tmp[256];
  int i = blockIdx.x * 256 + threadIdx.x;
  int v = (i < n) ? in[i] : 0;
  tmp[threadIdx.x] = v;
  __syncthreads();
  for (int off = 1; off < 256; off <<= 1) {
    int t = (threadIdx.x >= off) ? tmp[threadIdx.x - off] : 0;
    __syncthreads();
    tmp[threadIdx.x] += t;
    __syncthreads();
  }
  if (i < n) outv[i] = tmp[threadIdx.x] - v;  // exclusive within block
  if (threadIdx.x == 255) psum[blockIdx.x] = tmp[255];
}

__global__ __launch_bounds__(1024) void scan_psum_kernel(int* __restrict__ psum, int nb) {
  __shared__ int tmp[1024];
  int i = threadIdx.x;
  int v = (i < nb) ? psum[i] : 0;
  tmp[i] = v;
  __syncthreads();
  for (int off = 1; off < 1024; off <<= 1) {
    int t = (i >= off) ? tmp[i - off] : 0;
    __syncthreads();
    tmp[i] += t;
    __syncthreads();
  }
  if (i < nb) psum[i] = tmp[i] - v;  // exclusive
}

__global__ void scan_add_kernel(int* __restrict__ v, const int* __restrict__ psum, int n) {
  int i = blockIdx.x * 256 + threadIdx.x;
  if (i < n) v[i] += psum[blockIdx.x];
}

// offs[b] = scanned histG[b*NBLK]; offs[NB] = E
__global__ void extract_offs_kernel(const int* __restrict__ histG, int* __restrict__ offs,
                                    int NB, int E) {
  int i = blockIdx.x * 256 + threadIdx.x;
  if (i < NB) offs[i] = histG[i * NBLK];
  if (i == NB) offs[NB] = E;
}

// ---------------- partition pass 2: scatter via LDS cursors ----------------
template <int SHIFT>
__global__ __launch_bounds__(256) void part_scatter_kernel(const int* __restrict__ src,
                                                           const int* __restrict__ dst,
                                                           const int* __restrict__ histG,
                                                           int* __restrict__ bins,
                                                           int E, int chunk, int NB) {
  __shared__ int cur[1024];
  const int k = blockIdx.x;
  for (int i = threadIdx.x; i < NB; i += 256) cur[i] = histG[i * NBLK + k];
  __syncthreads();
  const int lo = k * chunk, hi = min(E, lo + chunk);
  for (int e = lo + (int)threadIdx.x; e < hi; e += 256) {
    int d = dst[e];
    int b = d >> SHIFT;
    int pos = atomicAdd(&cur[b], 1);  // LDS atomic, block-private; global pos unique
    bins[pos] = src[e] | ((d & ((1 << SHIFT) - 1)) << 18);
  }
}

// exact per-node degree from binned edges (streamed reads, LDS histogram)
template <int NPB>
__global__ __launch_bounds__(256) void bucket_deg_kernel(const int* __restrict__ bins,
                                                         const int* __restrict__ offs,
                                                         float* __restrict__ dinv, int n) {
  __shared__ int scnt[NPB];
  const int bb = blockIdx.x;
  for (int i = threadIdx.x; i < NPB; i += 256) scnt[i] = 0;
  __syncthreads();
  const int start = offs[bb], end = offs[bb + 1];
  for (int e = start + (int)threadIdx.x; e < end; e += 256)
    atomicAdd(&scnt[bins[e] >> 18], 1);
  __syncthreads();
  for (int i = threadIdx.x; i < NPB; i += 256) {
    int node = bb * NPB + i;
    if (node < n) dinv[node] = rsqrtf((float)scnt[i] + 1.0f);  // +1 = self loop
  }
}

// ---------------- bucket gather: block owns a bucket, LDS accumulators ----------------
template <int C, int NPB, int HSHIFT>
__global__ __launch_bounds__(512) void bucket_gather_kernel(const int* __restrict__ bins,
                                                            const int* __restrict__ offs,
                                                            const float* __restrict__ dinv,
                                                            const float* __restrict__ h,
                                                            const float* __restrict__ b,
                                                            float* __restrict__ out, int n) {
  __shared__ float acc[NPB * C];
  const int tid = threadIdx.x;
  const int bb = blockIdx.x;
  const int nodebase = bb * NPB;
  for (int idx = tid; idx < NPB * C; idx += 512) {  // init with self-loop term
    int node = nodebase + idx / C;
    int c = idx % C;
    float v = 0.f;
    if (node < n) v = dinv[node] * h[((long)(node >> HSHIFT)) * C + c];
    acc[idx] = v;
  }
  __syncthreads();
  const int start = offs[bb], end = offs[bb + 1];
  constexpr int LPE = (C < 64) ? C : 64;  // lanes per edge
  constexpr int EPW = 64 / LPE;           // edges per wave-iteration
  constexpr int VEC = (C + 63) / 64;      // channel chunks per lane
  const int wave = tid >> 6;
  const int lane = tid & 63;
  const int sub = lane / LPE;
  const int c0 = lane % LPE;
  for (int e0 = start + wave * EPW; e0 < end; e0 += 8 * EPW) {
    int e = e0 + sub;
    if (e < end) {
      int p = bins[e];
      int s = p & 0x3FFFF;
      int dl = p >> 18;
      float w = dinv[s];
      long row = ((long)(s >> HSHIFT)) * C;
#pragma unroll
      for (int v = 0; v < VEC; v++) {
        int c = c0 + v * 64;
        atomicAdd(&acc[dl * C + c], w * h[row + c]);  // ds_add_f32
      }
    }
  }
  __syncthreads();
  for (int idx = tid; idx < NPB * C; idx += 512) {
    int node = nodebase + idx / C;
    if (node < n) {
      int c = idx % C;
      out[(long)node * C + c] = fmaf(dinv[node], acc[idx], b[c]);
    }
  }
}

// ---------------- GEMMs (unchanged, proven) ----------------
template <int CIN, int COUT, bool RELU>
__global__ __launch_bounds__(256) void gemm_tiled(const float* __restrict__ x,
                                                  const float* __restrict__ W,
                                                  float* __restrict__ h, int n) {
  constexpr int TM = 32, KT = 32, TR = 4;
  constexpr int TC = COUT / 32;
  __shared__ float xs[TM][KT + 1];
  __shared__ float ws[KT][COUT];
  const int tid = threadIdx.x;
  const int cg = tid & 31;
  const int rg = tid >> 5;
  const int c0 = cg * TC;
  const int r0 = rg * TR;
  const int rowbase = blockIdx.x * TM;
  float acc[TR][TC];
#pragma unroll
  for (int i = 0; i < TR; i++)
#pragma unroll
    for (int j = 0; j < TC; j++) acc[i][j] = 0.f;

  for (int k0 = 0; k0 < CIN; k0 += KT) {
    __syncthreads();
#pragma unroll
    for (int t = 0; t < TM * KT / 256; t++) {
      int idx = tid + t * 256;
      int r = idx >> 5, k = idx & 31;
      int gr = rowbase + r;
      float v = 0.f;
      if (gr < n) {
        v = x[(long)gr * CIN + k0 + k];
        if (RELU) v = fmaxf(v, 0.f);
      }
      xs[r][k] = v;
    }
#pragma unroll
    for (int t = 0; t < KT * COUT / 256; t++) {
      int idx = tid + t * 256;
      int k = idx / COUT, c = idx % COUT;
      ws[k][c] = W[(long)(k0 + k) * COUT + c];
    }
    __syncthreads();
#pragma unroll 4
    for (int k = 0; k < KT; k++) {
      float a[TR], w[TC];
#pragma unroll
      for (int i = 0; i < TR; i++) a[i] = xs[r0 + i][k];
#pragma unroll
      for (int j = 0; j < TC; j++) w[j] = ws[k][c0 + j];
#pragma unroll
      for (int i = 0; i < TR; i++)
#pragma unroll
        for (int j = 0; j < TC; j++) acc[i][j] = fmaf(a[i], w[j], acc[i][j]);
    }
  }
#pragma unroll
  for (int i = 0; i < TR; i++) {
    int gr = rowbase + r0 + i;
    if (gr < n) {
#pragma unroll
      for (int j = 0; j < TC; j++) h[(long)gr * COUT + c0 + j] = acc[i][j];
    }
  }
}

template <int CIN, int COUT, int TM, bool RELU>
__global__ __launch_bounds__(256) void gemm_small(const float* __restrict__ x,
                                                  const float* __restrict__ W,
                                                  float* __restrict__ h, int n) {
  __shared__ float xs[TM][CIN + 1];
  const int tid = threadIdx.x;
  const int base = blockIdx.x * TM;
  for (int idx = tid; idx < TM * CIN; idx += 256) {
    int m = idx / CIN, k = idx - m * CIN;
    int r = base + m;
    float v = 0.f;
    if (r < n) {
      v = x[(long)r * CIN + k];
      if (RELU) v = fmaxf(v, 0.f);
    }
    xs[m][k] = v;
  }
  __syncthreads();
  constexpr int GROUPS = 256 / COUT;
  constexpr int ACC = TM / GROUPS;
  const int c = tid % COUT;
  const int mg = tid / COUT;
  float acc[ACC];
#pragma unroll
  for (int a = 0; a < ACC; a++) acc[a] = 0.f;
#pragma unroll 8
  for (int k = 0; k < CIN; k++) {
    float wk = W[k * COUT + c];
#pragma unroll
    for (int a = 0; a < ACC; a++) acc[a] = fmaf(xs[mg + a * GROUPS][k], wk, acc[a]);
  }
#pragma unroll
  for (int a = 0; a < ACC; a++) {
    int r = base + mg + a * GROUPS;
    if (r < n) h[(long)r * COUT + c] = acc[a];
  }
}

extern "C" void kernel_launch(void* const* d_in, const int* in_sizes, int n_in,
                              void* d_out, int out_size, void* d_ws, size_t ws_size,
                              hipStream_t stream) {
  const float* z  = (const float*)d_in[0];
  const int* ei   = (const int*)d_in[1];
  const int* ps2  = (const int*)d_in[2];
  const int* ps1  = (const int*)d_in[3];
  const int* ps0  = (const int*)d_in[4];
  const float* W1 = (const float*)d_in[5];  const float* b1 = (const float*)d_in[6];
  const float* W2 = (const float*)d_in[7];  const float* b2 = (const float*)d_in[8];
  const float* W3 = (const float*)d_in[9];  const float* b3 = (const float*)d_in[10];
  const float* W4 = (const float*)d_in[11]; const float* b4 = (const float*)d_in[12];
  float* out = (float*)d_out;

  const int N  = in_sizes[0] / 256;  // 25000
  const int E1 = in_sizes[1] / 2;    // 400000
  const int E2 = in_sizes[2] / 2;    // 800000
  const int E3 = in_sizes[3] / 2;    // 1600000
  const int E4 = in_sizes[4] / 2;    // 3200000
  const int n1 = N, n2 = 2 * N, n3 = 4 * N, n4 = 8 * N;
  // NPB per layer = 32/64/128/256 -> NB = 782 buckets for every layer
  const int NB = cdiv(n1, 32);
  const int NT = NB * NBLK;           // 200,704 histogram entries
  const int nbs = cdiv(NT, 256);      // 784 scan blocks (<= 1024)

  const long BUF = (long)N * 256;  // 6.4M floats per rotating buffer
  float* A  = (float*)d_ws;
  float* B  = A + BUF;
  float* Cb = B + BUF;

  // Per-layer aux pack (ints): hist[NT], psum[1024], offs[1024], bins[E], dinv[n] (f32).
  // Placed in provably-dead regions of the rotating buffers (liveness audited R3/R4).
  // L1: Cb base (Cb untouched until gemm2, which runs after gather1)
  int*   hist1 = (int*)Cb;
  int*   psum1 = hist1 + NT;
  int*   offs1 = psum1 + 1024;
  int*   bins1 = offs1 + 1024;
  float* dinv1 = (float*)(bins1 + E1);          // span ~2.5 MB << 25.6 MB
  // L2: Cb upper half (h2 = N*128 floats exactly fills lower half)
  int*   hist2 = (int*)(Cb + BUF / 2);
  int*   psum2 = hist2 + NT;
  int*   offs2 = psum2 + 1024;
  int*   bins2 = offs2 + 1024;
  float* dinv2 = (float*)(bins2 + E2);          // span ~4.2 MB <= 12.8 MB
  // L3: B upper half (out1 in B dead after gemm2; h3 fills B lower half)
  int*   hist3 = (int*)(B + BUF / 2);
  int*   psum3 = hist3 + NT;
  int*   offs3 = psum3 + 1024;
  int*   bins3 = offs3 + 1024;
  float* dinv3 = (float*)(bins3 + E3);          // span ~7.6 MB <= 12.8 MB
  // L4: B base (all of B dead after gather3)
  int*   hist4 = (int*)B;
  int*   psum4 = hist4 + NT;
  int*   offs4 = psum4 + 1024;
  int*   bins4 = offs4 + 1024;
  float* dinv4 = (float*)(bins4 + E4);          // span ~14.4 MB <= 25.6 MB

  // ---------------- Layer 1: h1=A (Nx256), out1=B ----------------
  {
    int chunk = cdiv(E1, NBLK);
    part_hist_kernel<5><<<NBLK, 256, 0, stream>>>(ei + E1, hist1, E1, chunk, NB);
    scan_block_kernel<<<nbs, 256, 0, stream>>>(hist1, hist1, psum1, NT);
    scan_psum_kernel<<<1, 1024, 0, stream>>>(psum1, nbs);
    scan_add_kernel<<<nbs, 256, 0, stream>>>(hist1, psum1, NT);
    extract_offs_kernel<<<cdiv(NB + 1, 256), 256, 0, stream>>>(hist1, offs1, NB, E1);
    part_scatter_kernel<5><<<NBLK, 256, 0, stream>>>(ei, ei + E1, hist1, bins1, E1, chunk, NB);
    bucket_deg_kernel<32><<<NB, 256, 0, stream>>>(bins1, offs1, dinv1, n1);
    gemm_tiled<256, 256, false><<<cdiv(n1, 32), 256, 0, stream>>>(z, W1, A, n1);
    bucket_gather_kernel<256, 32, 0><<<NB, 512, 0, stream>>>(bins1, offs1, dinv1, A, b1, B, n1);
  }

  // ---------------- Layer 2: h2=Cb lower (Nx128), out2=A (2N x 128) ----------------
  {
    int chunk = cdiv(E2, NBLK);
    part_hist_kernel<6><<<NBLK, 256, 0, stream>>>(ps2 + E2, hist2, E2, chunk, NB);
    scan_block_kernel<<<nbs, 256, 0, stream>>>(hist2, hist2, psum2, NT);
    scan_psum_kernel<<<1, 1024, 0, stream>>>(psum2, nbs);
    scan_add_kernel<<<nbs, 256, 0, stream>>>(hist2, psum2, NT);
    extract_offs_kernel<<<cdiv(NB + 1, 256), 256, 0, stream>>>(hist2, offs2, NB, E2);
    part_scatter_kernel<6><<<NBLK, 256, 0, stream>>>(ps2, ps2 + E2, hist2, bins2, E2, chunk, NB);
    bucket_deg_kernel<64><<<NB, 256, 0, stream>>>(bins2, offs2, dinv2, n2);
    gemm_tiled<256, 128, true><<<cdiv(N, 32), 256, 0, stream>>>(B, W2, Cb, N);
    bucket_gather_kernel<128, 64, 1><<<NB, 512, 0, stream>>>(bins2, offs2, dinv2, Cb, b2, A, n2);
  }

  // ---------------- Layer 3: h3=B lower (2N x 64), out3=Cb (4N x 64) ----------------
  {
    int chunk = cdiv(E3, NBLK);
    part_hist_kernel<7><<<NBLK, 256, 0, stream>>>(ps1 + E3, hist3, E3, chunk, NB);
    scan_block_kernel<<<nbs, 256, 0, stream>>>(hist3, hist3, psum3, NT);
    scan_psum_kernel<<<1, 1024, 0, stream>>>(psum3, nbs);
    scan_add_kernel<<<nbs, 256, 0, stream>>>(hist3, psum3, NT);
    extract_offs_kernel<<<cdiv(NB + 1, 256), 256, 0, stream>>>(hist3, offs3, NB, E3);
    part_scatter_kernel<7><<<NBLK, 256, 0, stream>>>(ps1, ps1 + E3, hist3, bins3, E3, chunk, NB);
    bucket_deg_kernel<128><<<NB, 256, 0, stream>>>(bins3, offs3, dinv3, n3);
    gemm_tiled<128, 64, true><<<cdiv(2 * N, 32), 256, 0, stream>>>(A, W3, B, 2 * N);
    bucket_gather_kernel<64, 128, 1><<<NB, 512, 0, stream>>>(bins3, offs3, dinv3, B, b3, Cb, n3);
  }

  // ---------------- Layer 4: h4=A base (4N x 8), out4=d_out (8N x 8) ----------------
  {
    int chunk = cdiv(E4, NBLK);
    part_hist_kernel<8><<<NBLK, 256, 0, stream>>>(ps0 + E4, hist4, E4, chunk, NB);
    scan_block_kernel<<<nbs, 256, 0, stream>>>(hist4, hist4, psum4, NT);
    scan_psum_kernel<<<1, 1024, 0, stream>>>(psum4, nbs);
    scan_add_kernel<<<nbs, 256, 0, stream>>>(hist4, psum4, NT);
    extract_offs_kernel<<<cdiv(NB + 1, 256), 256, 0, stream>>>(hist4, offs4, NB, E4);
    part_scatter_kernel<8><<<NBLK, 256, 0, stream>>>(ps0, ps0 + E4, hist4, bins4, E4, chunk, NB);
    bucket_deg_kernel<256><<<NB, 256, 0, stream>>>(bins4, offs4, dinv4, n4);
    gemm_small<64, 8, 32, true><<<cdiv(4 * N, 32), 256, 0, stream>>>(Cb, W4, A, 4 * N);
    bucket_gather_kernel<8, 256, 1><<<NB, 512, 0, stream>>>(bins4, offs4, dinv4, A, b4, out, n4);
  }
}

// Round 6
// 931.090 us; speedup vs baseline: 5.7799x; 2.9822x over previous
//
#include <hip/hip_runtime.h>

// GCN decoder: 4 x (deterministic radix partition -> per-node CSR -> register-acc gather
//                   + register-tiled fp32 GEMM).
// upsample2 identity: h = upsample2(x) @ W has h[2i]==h[2i+1] -> compute h on the
// pre-upsample node set, index with (node >> HSHIFT).
// Aggregation: out[d][c] = b[c] + dinv[d]*( dinv[d]*h[d>>s][c] + sum_{e:dst=d} dinv[src]*h[src>>s][c] )
// History: R2 global-atomic scatter (347us/layer) -> R3 exact CSR w/ per-node global atomics
// (fill 166us write-amp-bound) -> R4 782 global cursors (748us contention-bound) ->
// R5 deterministic 2-pass partition (good) + bucket LDS-atomic gather (695us latency-bound).
// R6 = R5's partition + csrify bridge + R3's proven per-node register gather.

static inline int cdiv(long a, int b) { return (int)((a + b - 1) / b); }

static constexpr int NBLK = 256;  // partition blocks

// ---------------- partition pass 1: per-block histogram (bucket-major write) ----------------
template <int SHIFT>
__global__ __launch_bounds__(256) void part_hist_kernel(const int* __restrict__ dst,
                                                        int* __restrict__ histG,
                                                        int E, int chunk, int NB) {
  __shared__ int hist[1024];
  for (int i = threadIdx.x; i < NB; i += 256) hist[i] = 0;
  __syncthreads();
  const int k = blockIdx.x;
  const int lo = k * chunk, hi = min(E, lo + chunk);
  for (int e = lo + (int)threadIdx.x; e < hi; e += 256)
    atomicAdd(&hist[dst[e] >> SHIFT], 1);  // LDS atomic, block-private
  __syncthreads();
  for (int i = threadIdx.x; i < NB; i += 256)
    histG[i * NBLK + k] = hist[i];
}

// ---------------- 3-kernel exclusive scan (in-place safe) ----------------
__global__ void scan_block_kernel(const int* __restrict__ in, int* __restrict__ outv,
                                  int* __restrict__ psum, int n) {
  __shared__ int tmp[256];
  int i = blockIdx.x * 256 + threadIdx.x;
  int v = (i < n) ? in[i] : 0;
  tmp[threadIdx.x] = v;
  __syncthreads();
  for (int off = 1; off < 256; off <<= 1) {
    int t = (threadIdx.x >= off) ? tmp[threadIdx.x - off] : 0;
    __syncthreads();
    tmp[threadIdx.x] += t;
    __syncthreads();
  }
  if (i < n) outv[i] = tmp[threadIdx.x] - v;
  if (threadIdx.x == 255) psum[blockIdx.x] = tmp[255];
}

__global__ __launch_bounds__(1024) void scan_psum_kernel(int* __restrict__ psum, int nb) {
  __shared__ int tmp[1024];
  int i = threadIdx.x;
  int v = (i < nb) ? psum[i] : 0;
  tmp[i] = v;
  __syncthreads();
  for (int off = 1; off < 1024; off <<= 1) {
    int t = (i >= off) ? tmp[i - off] : 0;
    __syncthreads();
    tmp[i] += t;
    __syncthreads();
  }
  if (i < nb) psum[i] = tmp[i] - v;
}

__global__ void scan_add_kernel(int* __restrict__ v, const int* __restrict__ psum, int n) {
  int i = blockIdx.x * 256 + threadIdx.x;
  if (i < n) v[i] += psum[blockIdx.x];
}

// boffs[b] = scanned histG[b*NBLK]; boffs[NB] = E
__global__ void extract_offs_kernel(const int* __restrict__ histG, int* __restrict__ boffs,
                                    int NB, int E) {
  int i = blockIdx.x * 256 + threadIdx.x;
  if (i < NB) boffs[i] = histG[i * NBLK];
  if (i == NB) boffs[NB] = E;
}

// ---------------- partition pass 2: scatter via LDS cursors ----------------
template <int SHIFT>
__global__ __launch_bounds__(256) void part_scatter_kernel(const int* __restrict__ src,
                                                           const int* __restrict__ dst,
                                                           const int* __restrict__ histG,
                                                           int* __restrict__ bins,
                                                           int E, int chunk, int NB) {
  __shared__ int cur[1024];
  const int k = blockIdx.x;
  for (int i = threadIdx.x; i < NB; i += 256) cur[i] = histG[i * NBLK + k];
  __syncthreads();
  const int lo = k * chunk, hi = min(E, lo + chunk);
  for (int e = lo + (int)threadIdx.x; e < hi; e += 256) {
    int d = dst[e];
    int b = d >> SHIFT;
    int pos = atomicAdd(&cur[b], 1);  // LDS atomic; global pos unique by construction
    bins[pos] = src[e] | ((d & ((1 << SHIFT) - 1)) << 18);
  }
}

// ---------------- csrify: bucket bins -> exact per-node CSR + noffs + dinv ----------------
// One block per bucket. noffs is globally monotone (contiguous across buckets); noffs[n]=E.
template <int NPB>
__global__ __launch_bounds__(256) void csrify_kernel(const int* __restrict__ bins,
                                                     const int* __restrict__ boffs,
                                                     int* __restrict__ csr,
                                                     int* __restrict__ noffs,
                                                     float* __restrict__ dinv,
                                                     int n, int E, int NBtot) {
  __shared__ int cnt[NPB];
  __shared__ int scanv[NPB];
  __shared__ int cur[NPB];
  const int bb = blockIdx.x;
  const int tid = threadIdx.x;
  if (tid < NPB) cnt[tid] = 0;
  __syncthreads();
  const int start = boffs[bb], end = boffs[bb + 1];
  for (int e = start + tid; e < end; e += 256) atomicAdd(&cnt[bins[e] >> 18], 1);
  __syncthreads();
  if (tid < NPB) scanv[tid] = cnt[tid];
  __syncthreads();
  for (int off = 1; off < NPB; off <<= 1) {
    int t = 0;
    if (tid < NPB && tid >= off) t = scanv[tid - off];
    __syncthreads();
    if (tid < NPB) scanv[tid] += t;
    __syncthreads();
  }
  if (tid < NPB) {
    int excl = scanv[tid] - cnt[tid];
    cur[tid] = excl;
    int node = bb * NPB + tid;
    if (node < n) {
      noffs[node] = start + excl;
      dinv[node] = rsqrtf((float)cnt[tid] + 1.0f);  // +1 = self loop
    }
  }
  if (bb == NBtot - 1 && tid == 0) noffs[n] = E;
  __syncthreads();
  for (int e = start + tid; e < end; e += 256) {
    int p = bins[e];
    int dl = p >> 18;
    int pos = start + atomicAdd(&cur[dl], 1);
    csr[pos] = p & 0x3FFFF;
  }
}

// ---------------- per-node gather: register accumulation, channel per thread ----------------
template <int C, int HSHIFT>
__global__ __launch_bounds__(256) void node_gather_kernel(const int* __restrict__ csr,
                                                          const int* __restrict__ noffs,
                                                          const float* __restrict__ dinv,
                                                          const float* __restrict__ h,
                                                          const float* __restrict__ b,
                                                          float* __restrict__ out, int n) {
  constexpr int NPB = 256 / C;  // nodes per block: 1 / 2 / 4 / 32
  const int node = blockIdx.x * NPB + threadIdx.x / C;
  const int c = threadIdx.x % C;
  if (node >= n) return;
  const int start = noffs[node];
  const int end = noffs[node + 1];
  const float dd = dinv[node];
  float acc = dd * h[((long)(node >> HSHIFT)) * C + c];  // self loop
  int j = start;
  for (; j + 1 < end; j += 2) {
    int s0 = csr[j], s1 = csr[j + 1];
    float w0 = dinv[s0], w1 = dinv[s1];
    float h0 = h[((long)(s0 >> HSHIFT)) * C + c];
    float h1 = h[((long)(s1 >> HSHIFT)) * C + c];
    acc = fmaf(w0, h0, acc);
    acc = fmaf(w1, h1, acc);
  }
  if (j < end) {
    int s0 = csr[j];
    acc = fmaf(dinv[s0], h[((long)(s0 >> HSHIFT)) * C + c], acc);
  }
  out[(long)node * C + c] = fmaf(dd, acc, b[c]);
}

// ---------------- GEMMs (unchanged, proven) ----------------
template <int CIN, int COUT, bool RELU>
__global__ __launch_bounds__(256) void gemm_tiled(const float* __restrict__ x,
                                                  const float* __restrict__ W,
                                                  float* __restrict__ h, int n) {
  constexpr int TM = 32, KT = 32, TR = 4;
  constexpr int TC = COUT / 32;
  __shared__ float xs[TM][KT + 1];
  __shared__ float ws[KT][COUT];
  const int tid = threadIdx.x;
  const int cg = tid & 31;
  const int rg = tid >> 5;
  const int c0 = cg * TC;
  const int r0 = rg * TR;
  const int rowbase = blockIdx.x * TM;
  float acc[TR][TC];
#pragma unroll
  for (int i = 0; i < TR; i++)
#pragma unroll
    for (int j = 0; j < TC; j++) acc[i][j] = 0.f;

  for (int k0 = 0; k0 < CIN; k0 += KT) {
    __syncthreads();
#pragma unroll
    for (int t = 0; t < TM * KT / 256; t++) {
      int idx = tid + t * 256;
      int r = idx >> 5, k = idx & 31;
      int gr = rowbase + r;
      float v = 0.f;
      if (gr < n) {
        v = x[(long)gr * CIN + k0 + k];
        if (RELU) v = fmaxf(v, 0.f);
      }
      xs[r][k] = v;
    }
#pragma unroll
    for (int t = 0; t < KT * COUT / 256; t++) {
      int idx = tid + t * 256;
      int k = idx / COUT, c = idx % COUT;
      ws[k][c] = W[(long)(k0 + k) * COUT + c];
    }
    __syncthreads();
#pragma unroll 4
    for (int k = 0; k < KT; k++) {
      float a[TR], w[TC];
#pragma unroll
      for (int i = 0; i < TR; i++) a[i] = xs[r0 + i][k];
#pragma unroll
      for (int j = 0; j < TC; j++) w[j] = ws[k][c0 + j];
#pragma unroll
      for (int i = 0; i < TR; i++)
#pragma unroll
        for (int j = 0; j < TC; j++) acc[i][j] = fmaf(a[i], w[j], acc[i][j]);
    }
  }
#pragma unroll
  for (int i = 0; i < TR; i++) {
    int gr = rowbase + r0 + i;
    if (gr < n) {
#pragma unroll
      for (int j = 0; j < TC; j++) h[(long)gr * COUT + c0 + j] = acc[i][j];
    }
  }
}

template <int CIN, int COUT, int TM, bool RELU>
__global__ __launch_bounds__(256) void gemm_small(const float* __restrict__ x,
                                                  const float* __restrict__ W,
                                                  float* __restrict__ h, int n) {
  __shared__ float xs[TM][CIN + 1];
  const int tid = threadIdx.x;
  const int base = blockIdx.x * TM;
  for (int idx = tid; idx < TM * CIN; idx += 256) {
    int m = idx / CIN, k = idx - m * CIN;
    int r = base + m;
    float v = 0.f;
    if (r < n) {
      v = x[(long)r * CIN + k];
      if (RELU) v = fmaxf(v, 0.f);
    }
    xs[m][k] = v;
  }
  __syncthreads();
  constexpr int GROUPS = 256 / COUT;
  constexpr int ACC = TM / GROUPS;
  const int c = tid % COUT;
  const int mg = tid / COUT;
  float acc[ACC];
#pragma unroll
  for (int a = 0; a < ACC; a++) acc[a] = 0.f;
#pragma unroll 8
  for (int k = 0; k < CIN; k++) {
    float wk = W[k * COUT + c];
#pragma unroll
    for (int a = 0; a < ACC; a++) acc[a] = fmaf(xs[mg + a * GROUPS][k], wk, acc[a]);
  }
#pragma unroll
  for (int a = 0; a < ACC; a++) {
    int r = base + mg + a * GROUPS;
    if (r < n) h[(long)r * COUT + c] = acc[a];
  }
}

extern "C" void kernel_launch(void* const* d_in, const int* in_sizes, int n_in,
                              void* d_out, int out_size, void* d_ws, size_t ws_size,
                              hipStream_t stream) {
  const float* z  = (const float*)d_in[0];
  const int* ei   = (const int*)d_in[1];
  const int* ps2  = (const int*)d_in[2];
  const int* ps1  = (const int*)d_in[3];
  const int* ps0  = (const int*)d_in[4];
  const float* W1 = (const float*)d_in[5];  const float* b1 = (const float*)d_in[6];
  const float* W2 = (const float*)d_in[7];  const float* b2 = (const float*)d_in[8];
  const float* W3 = (const float*)d_in[9];  const float* b3 = (const float*)d_in[10];
  const float* W4 = (const float*)d_in[11]; const float* b4 = (const float*)d_in[12];
  float* out = (float*)d_out;

  const int N  = in_sizes[0] / 256;  // 25000
  const int E1 = in_sizes[1] / 2;    // 400000
  const int E2 = in_sizes[2] / 2;    // 800000
  const int E3 = in_sizes[3] / 2;    // 1600000
  const int E4 = in_sizes[4] / 2;    // 3200000
  const int n1 = N, n2 = 2 * N, n3 = 4 * N, n4 = 8 * N;
  // NPB per layer = 32/64/128/256 -> NB = 782 buckets every layer
  const int NB = cdiv(n1, 32);
  const int NT = NB * NBLK;           // 200,704 histogram entries
  const int nbs = cdiv(NT, 256);      // 784 scan blocks (<= 1024)

  const long BUF = (long)N * 256;  // 6.4M floats per rotating buffer (x3 = 76.8 MB)
  float* A  = (float*)d_ws;
  float* B  = A + BUF;
  float* Cb = B + BUF;

  // Aux layout per layer: hist[NT], psum[1024], boffs[1024], [bins[E]], csr[E],
  // noffs[n+1], dinv[n]. Liveness audit (order per layer: gemm -> part -> csrify -> gather):
  // L1 aux+bins in Cb base (~4.2 MB; Cb dead until gemm2 writes h2=Cb.lo after gather1).
  int*   hist1 = (int*)Cb;
  int*   psum1 = hist1 + NT;
  int*   boffs1= psum1 + 1024;
  int*   bins1 = boffs1 + 1024;
  int*   csr1  = bins1 + E1;
  int*   noffs1= csr1 + E1;
  float* dinv1 = (float*)(noffs1 + n1 + 1);
  // L2 aux+bins in Cb upper half (~7.6 MB <= 12.8; h2 fills Cb lower half exactly).
  int*   hist2 = (int*)(Cb + BUF / 2);
  int*   psum2 = hist2 + NT;
  int*   boffs2= psum2 + 1024;
  int*   bins2 = boffs2 + 1024;
  int*   csr2  = bins2 + E2;
  int*   noffs2= csr2 + E2;
  float* dinv2 = (float*)(noffs2 + n2 + 1);
  // L3: bins3 in A (dead after gemm3 reads out2=A; part3 runs post-gemm3). Rest in B upper
  // half (~8.0 MB <= 12.8; h3=gemm3 output fills B lower half; out1 in B dead after gemm2).
  int*   bins3 = (int*)A;
  int*   hist3 = (int*)(B + BUF / 2);
  int*   psum3 = hist3 + NT;
  int*   boffs3= psum3 + 1024;
  int*   csr3  = boffs3 + 1024;
  int*   noffs3= csr3 + E3;
  float* dinv3 = (float*)(noffs3 + n3 + 1);
  // L4: h4 = A base (0.8M floats); bins4 in A at +1M floats (12.8 MB, ends 16.8 <= 25.6).
  // Rest in B (~15.2 MB <= 25.6; B fully dead after gather3).
  int*   bins4 = (int*)(A + 1048576);
  int*   hist4 = (int*)B;
  int*   psum4 = hist4 + NT;
  int*   boffs4= psum4 + 1024;
  int*   csr4  = boffs4 + 1024;
  int*   noffs4= csr4 + E4;
  float* dinv4 = (float*)(noffs4 + n4 + 1);

  // ---------------- Layer 1: h1=A (Nx256), out1=B (Nx256) ----------------
  {
    gemm_tiled<256, 256, false><<<cdiv(n1, 32), 256, 0, stream>>>(z, W1, A, n1);
    int chunk = cdiv(E1, NBLK);
    part_hist_kernel<5><<<NBLK, 256, 0, stream>>>(ei + E1, hist1, E1, chunk, NB);
    scan_block_kernel<<<nbs, 256, 0, stream>>>(hist1, hist1, psum1, NT);
    scan_psum_kernel<<<1, 1024, 0, stream>>>(psum1, nbs);
    scan_add_kernel<<<nbs, 256, 0, stream>>>(hist1, psum1, NT);
    extract_offs_kernel<<<cdiv(NB + 1, 256), 256, 0, stream>>>(hist1, boffs1, NB, E1);
    part_scatter_kernel<5><<<NBLK, 256, 0, stream>>>(ei, ei + E1, hist1, bins1, E1, chunk, NB);
    csrify_kernel<32><<<NB, 256, 0, stream>>>(bins1, boffs1, csr1, noffs1, dinv1, n1, E1, NB);
    node_gather_kernel<256, 0><<<n1, 256, 0, stream>>>(csr1, noffs1, dinv1, A, b1, B, n1);
  }

  // ---------------- Layer 2: h2=Cb.lo (Nx128), out2=A (2N x 128) ----------------
  {
    gemm_tiled<256, 128, true><<<cdiv(N, 32), 256, 0, stream>>>(B, W2, Cb, N);
    int chunk = cdiv(E2, NBLK);
    part_hist_kernel<6><<<NBLK, 256, 0, stream>>>(ps2 + E2, hist2, E2, chunk, NB);
    scan_block_kernel<<<nbs, 256, 0, stream>>>(hist2, hist2, psum2, NT);
    scan_psum_kernel<<<1, 1024, 0, stream>>>(psum2, nbs);
    scan_add_kernel<<<nbs, 256, 0, stream>>>(hist2, psum2, NT);
    extract_offs_kernel<<<cdiv(NB + 1, 256), 256, 0, stream>>>(hist2, boffs2, NB, E2);
    part_scatter_kernel<6><<<NBLK, 256, 0, stream>>>(ps2, ps2 + E2, hist2, bins2, E2, chunk, NB);
    csrify_kernel<64><<<NB, 256, 0, stream>>>(bins2, boffs2, csr2, noffs2, dinv2, n2, E2, NB);
    node_gather_kernel<128, 1><<<cdiv(n2, 2), 256, 0, stream>>>(csr2, noffs2, dinv2, Cb, b2, A, n2);
  }

  // ---------------- Layer 3: h3=B.lo (2N x 64), out3=Cb (4N x 64) ----------------
  {
    gemm_tiled<128, 64, true><<<cdiv(2 * N, 32), 256, 0, stream>>>(A, W3, B, 2 * N);
    int chunk = cdiv(E3, NBLK);
    part_hist_kernel<7><<<NBLK, 256, 0, stream>>>(ps1 + E3, hist3, E3, chunk, NB);
    scan_block_kernel<<<nbs, 256, 0, stream>>>(hist3, hist3, psum3, NT);
    scan_psum_kernel<<<1, 1024, 0, stream>>>(psum3, nbs);
    scan_add_kernel<<<nbs, 256, 0, stream>>>(hist3, psum3, NT);
    extract_offs_kernel<<<cdiv(NB + 1, 256), 256, 0, stream>>>(hist3, boffs3, NB, E3);
    part_scatter_kernel<7><<<NBLK, 256, 0, stream>>>(ps1, ps1 + E3, hist3, bins3, E3, chunk, NB);
    csrify_kernel<128><<<NB, 256, 0, stream>>>(bins3, boffs3, csr3, noffs3, dinv3, n3, E3, NB);
    node_gather_kernel<64, 1><<<cdiv(n3, 4), 256, 0, stream>>>(csr3, noffs3, dinv3, B, b3, Cb, n3);
  }

  // ---------------- Layer 4: h4=A base (4N x 8), out4=d_out (8N x 8) ----------------
  {
    gemm_small<64, 8, 32, true><<<cdiv(4 * N, 32), 256, 0, stream>>>(Cb, W4, A, 4 * N);
    int chunk = cdiv(E4, NBLK);
    part_hist_kernel<8><<<NBLK, 256, 0, stream>>>(ps0 + E4, hist4, E4, chunk, NB);
    scan_block_kernel<<<nbs, 256, 0, stream>>>(hist4, hist4, psum4, NT);
    scan_psum_kernel<<<1, 1024, 0, stream>>>(psum4, nbs);
    scan_add_kernel<<<nbs, 256, 0, stream>>>(hist4, psum4, NT);
    extract_offs_kernel<<<cdiv(NB + 1, 256), 256, 0, stream>>>(hist4, boffs4, NB, E4);
    part_scatter_kernel<8><<<NBLK, 256, 0, stream>>>(ps0, ps0 + E4, hist4, bins4, E4, chunk, NB);
    csrify_kernel<256><<<NB, 256, 0, stream>>>(bins4, boffs4, csr4, noffs4, dinv4, n4, E4, NB);
    node_gather_kernel<8, 1><<<cdiv(n4, 32), 256, 0, stream>>>(csr4, noffs4, dinv4, A, b4, out, n4);
  }
}

// Round 8
// 747.357 us; speedup vs baseline: 7.2009x; 1.2458x over previous
//
#include <hip/hip_runtime.h>

// GCN decoder: batched deterministic radix partition -> in-place per-node CSR ->
// float4 register gather; register-tiled fp32 GEMMs.
// upsample2 identity: h = upsample2(x) @ W has h[2i]==h[2i+1] -> compute h on the
// pre-upsample node set, index with (node >> HSHIFT).
// out[d][c] = b[c] + dinv[d]*( dinv[d]*h[d>>s][c] + sum_{e:dst=d} dinv[src]*h[src>>s][c] )
// R6 post-mortem: gathers 121us (latency-bound, 4B/lane), partition ~350us across 24 tiny
// dispatches. R7: float4 gather (4x MLP) + layers-1-3 partition batched into one chain,
// csrify in-place (bins==csr, bucket staged in registers).
// R8 = R7 resubmitted verbatim (R7 bench hit GPUAcquisitionTimeout; hypothesis untested).

static inline int cdiv(long a, int b) { return (int)((a + b - 1) / b); }
static constexpr int NBLK = 256;  // partition blocks / histogram columns

// ---------------- batched partition, layers 1-3 (bucket space = 3*NB) ----------------
__global__ __launch_bounds__(256) void part_hist3_kernel(
    const int* __restrict__ d1, const int* __restrict__ d2, const int* __restrict__ d3,
    int* __restrict__ histG, int E1, int E12, int ET, int chunk, int NB) {
  __shared__ int hist[2400];
  for (int i = threadIdx.x; i < 3 * NB; i += 256) hist[i] = 0;
  __syncthreads();
  const int k = blockIdx.x;
  const int lo = k * chunk, hi = min(ET, lo + chunk);
  for (int e = lo + (int)threadIdx.x; e < hi; e += 256) {
    int l, ee;
    if (e < E1) { l = 0; ee = e; }
    else if (e < E12) { l = 1; ee = e - E1; }
    else { l = 2; ee = e - E12; }
    const int* dp = (l == 0) ? d1 : (l == 1) ? d2 : d3;
    int d = dp[ee];
    atomicAdd(&hist[l * NB + (d >> (5 + l))], 1);
  }
  __syncthreads();
  for (int i = threadIdx.x; i < 3 * NB; i += 256) histG[i * NBLK + k] = hist[i];
}

__global__ __launch_bounds__(256) void part_scatter3_kernel(
    const int* __restrict__ s1, const int* __restrict__ d1,
    const int* __restrict__ s2, const int* __restrict__ d2,
    const int* __restrict__ s3, const int* __restrict__ d3,
    const int* __restrict__ histG, int* __restrict__ bins,
    int E1, int E12, int ET, int chunk, int NB) {
  __shared__ int cur[2400];
  const int k = blockIdx.x;
  for (int i = threadIdx.x; i < 3 * NB; i += 256) cur[i] = histG[i * NBLK + k];
  __syncthreads();
  const int lo = k * chunk, hi = min(ET, lo + chunk);
  for (int e = lo + (int)threadIdx.x; e < hi; e += 256) {
    int l, ee;
    if (e < E1) { l = 0; ee = e; }
    else if (e < E12) { l = 1; ee = e - E1; }
    else { l = 2; ee = e - E12; }
    const int* sp = (l == 0) ? s1 : (l == 1) ? s2 : s3;
    const int* dp = (l == 0) ? d1 : (l == 1) ? d2 : d3;
    int d = dp[ee];
    int sh = 5 + l;
    int pos = atomicAdd(&cur[l * NB + (d >> sh)], 1);  // LDS atomic; global pos unique
    bins[pos] = sp[ee] | ((d & ((1 << sh) - 1)) << 18);
  }
}

// ---------------- layer-4 partition (single layer, SHIFT=8) ----------------
__global__ __launch_bounds__(256) void part_hist4_kernel(const int* __restrict__ dst,
                                                         int* __restrict__ histG,
                                                         int E, int chunk, int NB) {
  __shared__ int hist[1024];
  for (int i = threadIdx.x; i < NB; i += 256) hist[i] = 0;
  __syncthreads();
  const int k = blockIdx.x;
  const int lo = k * chunk, hi = min(E, lo + chunk);
  for (int e = lo + (int)threadIdx.x; e < hi; e += 256)
    atomicAdd(&hist[dst[e] >> 8], 1);
  __syncthreads();
  for (int i = threadIdx.x; i < NB; i += 256) histG[i * NBLK + k] = hist[i];
}

__global__ __launch_bounds__(256) void part_scatter4_kernel(const int* __restrict__ src,
                                                            const int* __restrict__ dst,
                                                            const int* __restrict__ histG,
                                                            int* __restrict__ bins,
                                                            int E, int chunk, int NB) {
  __shared__ int cur[1024];
  const int k = blockIdx.x;
  for (int i = threadIdx.x; i < NB; i += 256) cur[i] = histG[i * NBLK + k];
  __syncthreads();
  const int lo = k * chunk, hi = min(E, lo + chunk);
  for (int e = lo + (int)threadIdx.x; e < hi; e += 256) {
    int d = dst[e];
    int pos = atomicAdd(&cur[d >> 8], 1);
    bins[pos] = src[e] | ((d & 255) << 18);
  }
}

// ---------------- 3-kernel scan primitives (in-place safe) ----------------
__global__ void scan_block_kernel(const int* __restrict__ in, int* __restrict__ outv,
                                  int* __restrict__ psum, int n) {
  __shared__ int tmp[256];
  int i = blockIdx.x * 256 + threadIdx.x;
  int v = (i < n) ? in[i] : 0;
  tmp[threadIdx.x] = v;
  __syncthreads();
  for (int off = 1; off < 256; off <<= 1) {
    int t = (threadIdx.x >= off) ? tmp[threadIdx.x - off] : 0;
    __syncthreads();
    tmp[threadIdx.x] += t;
    __syncthreads();
  }
  if (i < n) outv[i] = tmp[threadIdx.x] - v;
  if (threadIdx.x == 255) psum[blockIdx.x] = tmp[255];
}

__global__ __launch_bounds__(1024) void scan_psum_kernel(int* __restrict__ psum, int nb) {
  __shared__ int tmp[1024];
  int i = threadIdx.x;
  int v = (i < nb) ? psum[i] : 0;
  tmp[i] = v;
  __syncthreads();
  for (int off = 1; off < 1024; off <<= 1) {
    int t = (i >= off) ? tmp[i - off] : 0;
    __syncthreads();
    tmp[i] += t;
    __syncthreads();
  }
  if (i < nb) psum[i] = tmp[i] - v;
}

__global__ void scan_add_kernel(int* __restrict__ v, const int* __restrict__ psum, int n) {
  int i = blockIdx.x * 256 + threadIdx.x;
  if (i < n) v[i] += psum[blockIdx.x];
}

// boffs[g] = scanned histG[g*NBLK]; boffs[NBall] = Etot
__global__ void extract_offs_kernel(const int* __restrict__ histG, int* __restrict__ boffs,
                                    int NBall, int Etot) {
  int i = blockIdx.x * 256 + threadIdx.x;
  if (i < NBall) boffs[i] = histG[i * NBLK];
  if (i == NBall) boffs[NBall] = Etot;
}

// ---------------- in-place csrify: bins -> per-node CSR + noffs + dinv ----------------
// One block per bucket; whole bucket staged in registers (reads complete before writes).
__global__ __launch_bounds__(256) void csrify3_kernel(
    int* __restrict__ bins, const int* __restrict__ boffs,
    int* __restrict__ no1, int* __restrict__ no2, int* __restrict__ no3,
    float* __restrict__ dv1, float* __restrict__ dv2, float* __restrict__ dv3,
    int n1, int n2, int n3, int NB) {
  __shared__ int cnt[256];
  __shared__ int scanv[256];
  __shared__ int cur[256];
  const int bb = blockIdx.x;
  const int tid = threadIdx.x;
  const int l = bb / NB;
  const int lb = bb - l * NB;
  const int npb = 32 << l;                       // 32 / 64 / 128
  const int nl = (l == 0) ? n1 : (l == 1) ? n2 : n3;
  int* noffs = (l == 0) ? no1 : (l == 1) ? no2 : no3;
  float* dinv = (l == 0) ? dv1 : (l == 1) ? dv2 : dv3;
  cnt[tid] = 0;
  __syncthreads();
  const int start = boffs[bb], end = boffs[bb + 1];
  int rv[12];  // bucket <= 3072 edges (L3 mean 2046, +22 sigma headroom)
#pragma unroll
  for (int kk = 0; kk < 12; kk++) {
    int e = start + tid + kk * 256;
    rv[kk] = (e < end) ? bins[e] : -1;
    if (rv[kk] != -1) atomicAdd(&cnt[rv[kk] >> 18], 1);
  }
  __syncthreads();
  scanv[tid] = cnt[tid];
  __syncthreads();
  for (int off = 1; off < 256; off <<= 1) {
    int t = (tid >= off) ? scanv[tid - off] : 0;
    __syncthreads();
    scanv[tid] += t;
    __syncthreads();
  }
  int excl = scanv[tid] - cnt[tid];
  cur[tid] = excl;
  int node = lb * npb + tid;
  if (tid < npb && node < nl) {
    noffs[node] = start + excl;
    dinv[node] = rsqrtf((float)cnt[tid] + 1.0f);  // +1 = self loop
  }
  if (lb == NB - 1 && tid == 0) noffs[nl] = end;
  __syncthreads();
#pragma unroll
  for (int kk = 0; kk < 12; kk++) {
    if (rv[kk] != -1) {
      int dl = rv[kk] >> 18;
      int pos = start + atomicAdd(&cur[dl], 1);
      bins[pos] = rv[kk] & 0x3FFFF;  // in-place: all reads done before first write
    }
  }
}

__global__ __launch_bounds__(256) void csrify4_kernel(int* __restrict__ bins,
                                                      const int* __restrict__ boffs,
                                                      int* __restrict__ noffs,
                                                      float* __restrict__ dinv,
                                                      int n, int NB) {
  __shared__ int cnt[256];
  __shared__ int scanv[256];
  __shared__ int cur[256];
  const int bb = blockIdx.x;
  const int tid = threadIdx.x;
  cnt[tid] = 0;
  __syncthreads();
  const int start = boffs[bb], end = boffs[bb + 1];
  int rv[24];  // bucket <= 6144 edges (mean 4092, +32 sigma headroom)
#pragma unroll
  for (int kk = 0; kk < 24; kk++) {
    int e = start + tid + kk * 256;
    rv[kk] = (e < end) ? bins[e] : -1;
    if (rv[kk] != -1) atomicAdd(&cnt[rv[kk] >> 18], 1);
  }
  __syncthreads();
  scanv[tid] = cnt[tid];
  __syncthreads();
  for (int off = 1; off < 256; off <<= 1) {
    int t = (tid >= off) ? scanv[tid - off] : 0;
    __syncthreads();
    scanv[tid] += t;
    __syncthreads();
  }
  int excl = scanv[tid] - cnt[tid];
  cur[tid] = excl;
  int node = bb * 256 + tid;
  if (node < n) {
    noffs[node] = start + excl;
    dinv[node] = rsqrtf((float)cnt[tid] + 1.0f);
  }
  if (bb == NB - 1 && tid == 0) noffs[n] = end;
  __syncthreads();
#pragma unroll
  for (int kk = 0; kk < 24; kk++) {
    if (rv[kk] != -1) {
      int dl = rv[kk] >> 18;
      int pos = start + atomicAdd(&cur[dl], 1);
      bins[pos] = rv[kk] & 0x3FFFF;
    }
  }
}

// ---------------- float4 per-node gather: 4 channels/thread, register acc ----------------
template <int C, int HSHIFT>
__global__ __launch_bounds__(256) void node_gather4_kernel(const int* __restrict__ csr,
                                                           const int* __restrict__ noffs,
                                                           const float* __restrict__ dinv,
                                                           const float* __restrict__ h,
                                                           const float* __restrict__ b,
                                                           float* __restrict__ out, int n) {
  constexpr int LPN = C / 4;        // lanes per node: 64 / 32 / 16 / 2
  constexpr int NPB = 256 / LPN;    // nodes per block: 4 / 8 / 16 / 128
  const int node = blockIdx.x * NPB + threadIdx.x / LPN;
  const int c4 = (threadIdx.x % LPN) * 4;
  if (node >= n) return;
  const float4* __restrict__ h4 = reinterpret_cast<const float4*>(h);
  const int start = noffs[node];
  const int end = noffs[node + 1];
  const float dd = dinv[node];
  float4 sv = h4[(((long)(node >> HSHIFT)) * C + c4) >> 2];  // self loop
  float4 acc;
  acc.x = dd * sv.x; acc.y = dd * sv.y; acc.z = dd * sv.z; acc.w = dd * sv.w;
  int j = start;
  for (; j + 1 < end; j += 2) {
    int s0 = csr[j], s1 = csr[j + 1];
    float w0 = dinv[s0], w1 = dinv[s1];
    float4 v0 = h4[(((long)(s0 >> HSHIFT)) * C + c4) >> 2];
    float4 v1 = h4[(((long)(s1 >> HSHIFT)) * C + c4) >> 2];
    acc.x = fmaf(w0, v0.x, acc.x); acc.y = fmaf(w0, v0.y, acc.y);
    acc.z = fmaf(w0, v0.z, acc.z); acc.w = fmaf(w0, v0.w, acc.w);
    acc.x = fmaf(w1, v1.x, acc.x); acc.y = fmaf(w1, v1.y, acc.y);
    acc.z = fmaf(w1, v1.z, acc.z); acc.w = fmaf(w1, v1.w, acc.w);
  }
  if (j < end) {
    int s0 = csr[j];
    float w0 = dinv[s0];
    float4 v0 = h4[(((long)(s0 >> HSHIFT)) * C + c4) >> 2];
    acc.x = fmaf(w0, v0.x, acc.x); acc.y = fmaf(w0, v0.y, acc.y);
    acc.z = fmaf(w0, v0.z, acc.z); acc.w = fmaf(w0, v0.w, acc.w);
  }
  const float4 bb4 = *reinterpret_cast<const float4*>(b + c4);
  float4 o;
  o.x = fmaf(dd, acc.x, bb4.x); o.y = fmaf(dd, acc.y, bb4.y);
  o.z = fmaf(dd, acc.z, bb4.z); o.w = fmaf(dd, acc.w, bb4.w);
  *reinterpret_cast<float4*>(out + (long)node * C + c4) = o;
}

// ---------------- GEMMs (unchanged, proven) ----------------
template <int CIN, int COUT, bool RELU>
__global__ __launch_bounds__(256) void gemm_tiled(const float* __restrict__ x,
                                                  const float* __restrict__ W,
                                                  float* __restrict__ h, int n) {
  constexpr int TM = 32, KT = 32, TR = 4;
  constexpr int TC = COUT / 32;
  __shared__ float xs[TM][KT + 1];
  __shared__ float ws[KT][COUT];
  const int tid = threadIdx.x;
  const int cg = tid & 31;
  const int rg = tid >> 5;
  const int c0 = cg * TC;
  const int r0 = rg * TR;
  const int rowbase = blockIdx.x * TM;
  float acc[TR][TC];
#pragma unroll
  for (int i = 0; i < TR; i++)
#pragma unroll
    for (int j = 0; j < TC; j++) acc[i][j] = 0.f;

  for (int k0 = 0; k0 < CIN; k0 += KT) {
    __syncthreads();
#pragma unroll
    for (int t = 0; t < TM * KT / 256; t++) {
      int idx = tid + t * 256;
      int r = idx >> 5, k = idx & 31;
      int gr = rowbase + r;
      float v = 0.f;
      if (gr < n) {
        v = x[(long)gr * CIN + k0 + k];
        if (RELU) v = fmaxf(v, 0.f);
      }
      xs[r][k] = v;
    }
#pragma unroll
    for (int t = 0; t < KT * COUT / 256; t++) {
      int idx = tid + t * 256;
      int k = idx / COUT, c = idx % COUT;
      ws[k][c] = W[(long)(k0 + k) * COUT + c];
    }
    __syncthreads();
#pragma unroll 4
    for (int k = 0; k < KT; k++) {
      float a[TR], w[TC];
#pragma unroll
      for (int i = 0; i < TR; i++) a[i] = xs[r0 + i][k];
#pragma unroll
      for (int j = 0; j < TC; j++) w[j] = ws[k][c0 + j];
#pragma unroll
      for (int i = 0; i < TR; i++)
#pragma unroll
        for (int j = 0; j < TC; j++) acc[i][j] = fmaf(a[i], w[j], acc[i][j]);
    }
  }
#pragma unroll
  for (int i = 0; i < TR; i++) {
    int gr = rowbase + r0 + i;
    if (gr < n) {
#pragma unroll
      for (int j = 0; j < TC; j++) h[(long)gr * COUT + c0 + j] = acc[i][j];
    }
  }
}

template <int CIN, int COUT, int TM, bool RELU>
__global__ __launch_bounds__(256) void gemm_small(const float* __restrict__ x,
                                                  const float* __restrict__ W,
                                                  float* __restrict__ h, int n) {
  __shared__ float xs[TM][CIN + 1];
  const int tid = threadIdx.x;
  const int base = blockIdx.x * TM;
  for (int idx = tid; idx < TM * CIN; idx += 256) {
    int m = idx / CIN, k = idx - m * CIN;
    int r = base + m;
    float v = 0.f;
    if (r < n) {
      v = x[(long)r * CIN + k];
      if (RELU) v = fmaxf(v, 0.f);
    }
    xs[m][k] = v;
  }
  __syncthreads();
  constexpr int GROUPS = 256 / COUT;
  constexpr int ACC = TM / GROUPS;
  const int c = tid % COUT;
  const int mg = tid / COUT;
  float acc[ACC];
#pragma unroll
  for (int a = 0; a < ACC; a++) acc[a] = 0.f;
#pragma unroll 8
  for (int k = 0; k < CIN; k++) {
    float wk = W[k * COUT + c];
#pragma unroll
    for (int a = 0; a < ACC; a++) acc[a] = fmaf(xs[mg + a * GROUPS][k], wk, acc[a]);
  }
#pragma unroll
  for (int a = 0; a < ACC; a++) {
    int r = base + mg + a * GROUPS;
    if (r < n) h[(long)r * COUT + c] = acc[a];
  }
}

extern "C" void kernel_launch(void* const* d_in, const int* in_sizes, int n_in,
                              void* d_out, int out_size, void* d_ws, size_t ws_size,
                              hipStream_t stream) {
  const float* z  = (const float*)d_in[0];
  const int* ei   = (const int*)d_in[1];
  const int* ps2  = (const int*)d_in[2];
  const int* ps1  = (const int*)d_in[3];
  const int* ps0  = (const int*)d_in[4];
  const float* W1 = (const float*)d_in[5];  const float* b1 = (const float*)d_in[6];
  const float* W2 = (const float*)d_in[7];  const float* b2 = (const float*)d_in[8];
  const float* W3 = (const float*)d_in[9];  const float* b3 = (const float*)d_in[10];
  const float* W4 = (const float*)d_in[11]; const float* b4 = (const float*)d_in[12];
  float* out = (float*)d_out;

  const int N  = in_sizes[0] / 256;  // 25000
  const int E1 = in_sizes[1] / 2;    // 400000
  const int E2 = in_sizes[2] / 2;    // 800000
  const int E3 = in_sizes[3] / 2;    // 1600000
  const int E4 = in_sizes[4] / 2;    // 3200000
  const int n1 = N, n2 = 2 * N, n3 = 4 * N, n4 = 8 * N;
  const int E12 = E1 + E2, ETA = E1 + E2 + E3;  // combined L1-3 edge space
  const int NB = cdiv(n1, 32);       // 782 buckets/layer (NPB = 32<<l keeps NB constant)
  const int NB3 = 3 * NB;
  const int NTA = NB3 * NBLK;        // 600,576
  const int nbsA = cdiv(NTA, 256);   // 2347
  const int nbsA2 = cdiv(nbsA, 256); // 10
  const int NTB = NB * NBLK;         // 200,704
  const int nbsB = cdiv(NTB, 256);   // 784

  // ---- workspace map (proven bound: 3*6.4M floats = 76.8 MB; this uses ~68.9 MB) ----
  // F region [0 .. 12.8M floats): rotating features + parked csr4
  //   L1: h1=[0,6.4M) out1=[6.4M,12.8M)
  //   then: h2=[0,3.2M) csr4=[3.2M,6.4M) (built after gather1, read by gather4)
  //         out2/out3=[6.4M,12.8M), h3=[0,3.2M), h4=[0,0.8M)
  // P region [12.8M ..): csr123 (ETA ints, == binsA, csrify in-place), noffs1-4, dinv1-4
  // S region: histA, psumA, psumB, boffsA, histB, psumC, boffsB
  float* F = (float*)d_ws;
  float* h1 = F;                 // 25.6 MB
  float* out1 = F + 6400000;     // 25.6 MB
  float* h2 = F;                 // 12.8 MB
  int* binsB = (int*)(F + 3200000);  // csr4, 12.8 MB
  float* out2 = F + 6400000;
  float* h3 = F;
  float* out3 = F + 6400000;
  float* h4 = F;

  int* P = (int*)(F + 12800000);
  int* binsA = P;                         // ETA ints (csr123 after in-place csrify)
  int* no1 = P + ETA;                     // n1+1
  int* no2 = no1 + (n1 + 1);
  int* no3 = no2 + (n2 + 1);
  int* no4 = no3 + (n3 + 1);
  float* dv1 = (float*)(no4 + (n4 + 1));
  float* dv2 = dv1 + n1;
  float* dv3 = dv2 + n2;
  float* dv4 = dv3 + n3;
  int* S = (int*)(dv4 + n4);
  int* histA = S;                         // NTA
  int* psumA = histA + NTA;               // 3200
  int* psumB = psumA + 3200;              // 64
  int* boffsA = psumB + 64;               // NB3+1
  int* histB = boffsA + (NB3 + 1);        // NTB
  int* psumC = histB + NTB;               // 1024
  int* boffsB = psumC + 1024;             // NB+1

  // ---------------- partition layers 1-3 (one batched chain) ----------------
  {
    int chunk = cdiv(ETA, NBLK);
    part_hist3_kernel<<<NBLK, 256, 0, stream>>>(ei + E1, ps2 + E2, ps1 + E3, histA,
                                                E1, E12, ETA, chunk, NB);
    scan_block_kernel<<<nbsA, 256, 0, stream>>>(histA, histA, psumA, NTA);
    scan_block_kernel<<<nbsA2, 256, 0, stream>>>(psumA, psumA, psumB, nbsA);
    scan_psum_kernel<<<1, 1024, 0, stream>>>(psumB, nbsA2);
    scan_add_kernel<<<nbsA2, 256, 0, stream>>>(psumA, psumB, nbsA);
    scan_add_kernel<<<nbsA, 256, 0, stream>>>(histA, psumA, NTA);
    extract_offs_kernel<<<cdiv(NB3 + 1, 256), 256, 0, stream>>>(histA, boffsA, NB3, ETA);
    part_scatter3_kernel<<<NBLK, 256, 0, stream>>>(ei, ei + E1, ps2, ps2 + E2, ps1, ps1 + E3,
                                                   histA, binsA, E1, E12, ETA, chunk, NB);
    csrify3_kernel<<<NB3, 256, 0, stream>>>(binsA, boffsA, no1, no2, no3,
                                            dv1, dv2, dv3, n1, n2, n3, NB);
  }
  // layer-4 hist+scan upfront (touches only S region)
  {
    int chunk4 = cdiv(E4, NBLK);
    part_hist4_kernel<<<NBLK, 256, 0, stream>>>(ps0 + E4, histB, E4, chunk4, NB);
    scan_block_kernel<<<nbsB, 256, 0, stream>>>(histB, histB, psumC, NTB);
    scan_psum_kernel<<<1, 1024, 0, stream>>>(psumC, nbsB);
    scan_add_kernel<<<nbsB, 256, 0, stream>>>(histB, psumC, NTB);
    extract_offs_kernel<<<cdiv(NB + 1, 256), 256, 0, stream>>>(histB, boffsB, NB, E4);
  }

  // ---------------- Layer 1: h1 (Nx256), out1 ----------------
  gemm_tiled<256, 256, false><<<cdiv(n1, 32), 256, 0, stream>>>(z, W1, h1, n1);
  node_gather4_kernel<256, 0><<<cdiv(n1, 4), 256, 0, stream>>>(binsA, no1, dv1, h1, b1, out1, n1);

  // layer-4 scatter+csrify (binsB overlays dead h1 upper half; after gather1)
  {
    int chunk4 = cdiv(E4, NBLK);
    part_scatter4_kernel<<<NBLK, 256, 0, stream>>>(ps0, ps0 + E4, histB, binsB, E4, chunk4, NB);
    csrify4_kernel<<<NB, 256, 0, stream>>>(binsB, boffsB, no4, dv4, n4, NB);
  }

  // ---------------- Layer 2: h2 (Nx128), out2 (2N x 128) ----------------
  gemm_tiled<256, 128, true><<<cdiv(N, 32), 256, 0, stream>>>(out1, W2, h2, N);
  node_gather4_kernel<128, 1><<<cdiv(n2, 8), 256, 0, stream>>>(binsA, no2, dv2, h2, b2, out2, n2);

  // ---------------- Layer 3: h3 (2N x 64), out3 (4N x 64) ----------------
  gemm_tiled<128, 64, true><<<cdiv(2 * N, 32), 256, 0, stream>>>(out2, W3, h3, 2 * N);
  node_gather4_kernel<64, 1><<<cdiv(n3, 16), 256, 0, stream>>>(binsA, no3, dv3, h3, b3, out3, n3);

  // ---------------- Layer 4: h4 (4N x 8), out4 = d_out (8N x 8) ----------------
  gemm_small<64, 8, 32, true><<<cdiv(4 * N, 32), 256, 0, stream>>>(out3, W4, h4, 4 * N);
  node_gather4_kernel<8, 1><<<cdiv(n4, 128), 256, 0, stream>>>(binsB, no4, dv4, h4, b4, out, n4);
}

// Round 9
// 699.379 us; speedup vs baseline: 7.6949x; 1.0686x over previous
//
#include <hip/hip_runtime.h>

// GCN decoder: batched deterministic radix partition -> in-place per-node CSR ->
// float4 register gather; column-split transposed-LDS fp32 GEMMs (gemm_t).
// upsample2 identity: h = upsample2(x) @ W has h[2i]==h[2i+1] -> compute h on the
// pre-upsample node set, index with (node >> HSHIFT).
// out[d][c] = b[c] + dinv[d]*( dinv[d]*h[d>>s][c] + sum_{e:dst=d} dinv[src]*h[src>>s][c] )
// R8 post-mortem: GEMMs are the top dispatches (80us each): gemm1 8-way ws bank conflicts
// (6.4M), gemm2 latency-bound (VALUBusy 17%, 782 blocks). R9: gemm_t = TC=4 (conflict-free
// b128 ws read), transposed xs_t (b128/b64 A read), column-split grids (1564 blocks).

static inline int cdiv(long a, int b) { return (int)((a + b - 1) / b); }
static constexpr int NBLK = 256;  // partition blocks / histogram columns

// ---------------- batched partition, layers 1-3 (bucket space = 3*NB) ----------------
__global__ __launch_bounds__(256) void part_hist3_kernel(
    const int* __restrict__ d1, const int* __restrict__ d2, const int* __restrict__ d3,
    int* __restrict__ histG, int E1, int E12, int ET, int chunk, int NB) {
  __shared__ int hist[2400];
  for (int i = threadIdx.x; i < 3 * NB; i += 256) hist[i] = 0;
  __syncthreads();
  const int k = blockIdx.x;
  const int lo = k * chunk, hi = min(ET, lo + chunk);
  for (int e = lo + (int)threadIdx.x; e < hi; e += 256) {
    int l, ee;
    if (e < E1) { l = 0; ee = e; }
    else if (e < E12) { l = 1; ee = e - E1; }
    else { l = 2; ee = e - E12; }
    const int* dp = (l == 0) ? d1 : (l == 1) ? d2 : d3;
    int d = dp[ee];
    atomicAdd(&hist[l * NB + (d >> (5 + l))], 1);
  }
  __syncthreads();
  for (int i = threadIdx.x; i < 3 * NB; i += 256) histG[i * NBLK + k] = hist[i];
}

__global__ __launch_bounds__(256) void part_scatter3_kernel(
    const int* __restrict__ s1, const int* __restrict__ d1,
    const int* __restrict__ s2, const int* __restrict__ d2,
    const int* __restrict__ s3, const int* __restrict__ d3,
    const int* __restrict__ histG, int* __restrict__ bins,
    int E1, int E12, int ET, int chunk, int NB) {
  __shared__ int cur[2400];
  const int k = blockIdx.x;
  for (int i = threadIdx.x; i < 3 * NB; i += 256) cur[i] = histG[i * NBLK + k];
  __syncthreads();
  const int lo = k * chunk, hi = min(ET, lo + chunk);
  for (int e = lo + (int)threadIdx.x; e < hi; e += 256) {
    int l, ee;
    if (e < E1) { l = 0; ee = e; }
    else if (e < E12) { l = 1; ee = e - E1; }
    else { l = 2; ee = e - E12; }
    const int* sp = (l == 0) ? s1 : (l == 1) ? s2 : s3;
    const int* dp = (l == 0) ? d1 : (l == 1) ? d2 : d3;
    int d = dp[ee];
    int sh = 5 + l;
    int pos = atomicAdd(&cur[l * NB + (d >> sh)], 1);  // LDS atomic; global pos unique
    bins[pos] = sp[ee] | ((d & ((1 << sh) - 1)) << 18);
  }
}

// ---------------- layer-4 partition (single layer, SHIFT=8) ----------------
__global__ __launch_bounds__(256) void part_hist4_kernel(const int* __restrict__ dst,
                                                         int* __restrict__ histG,
                                                         int E, int chunk, int NB) {
  __shared__ int hist[1024];
  for (int i = threadIdx.x; i < NB; i += 256) hist[i] = 0;
  __syncthreads();
  const int k = blockIdx.x;
  const int lo = k * chunk, hi = min(E, lo + chunk);
  for (int e = lo + (int)threadIdx.x; e < hi; e += 256)
    atomicAdd(&hist[dst[e] >> 8], 1);
  __syncthreads();
  for (int i = threadIdx.x; i < NB; i += 256) histG[i * NBLK + k] = hist[i];
}

__global__ __launch_bounds__(256) void part_scatter4_kernel(const int* __restrict__ src,
                                                            const int* __restrict__ dst,
                                                            const int* __restrict__ histG,
                                                            int* __restrict__ bins,
                                                            int E, int chunk, int NB) {
  __shared__ int cur[1024];
  const int k = blockIdx.x;
  for (int i = threadIdx.x; i < NB; i += 256) cur[i] = histG[i * NBLK + k];
  __syncthreads();
  const int lo = k * chunk, hi = min(E, lo + chunk);
  for (int e = lo + (int)threadIdx.x; e < hi; e += 256) {
    int d = dst[e];
    int pos = atomicAdd(&cur[d >> 8], 1);
    bins[pos] = src[e] | ((d & 255) << 18);
  }
}

// ---------------- 3-kernel scan primitives (in-place safe) ----------------
__global__ void scan_block_kernel(const int* __restrict__ in, int* __restrict__ outv,
                                  int* __restrict__ psum, int n) {
  __shared__ int tmp[256];
  int i = blockIdx.x * 256 + threadIdx.x;
  int v = (i < n) ? in[i] : 0;
  tmp[threadIdx.x] = v;
  __syncthreads();
  for (int off = 1; off < 256; off <<= 1) {
    int t = (threadIdx.x >= off) ? tmp[threadIdx.x - off] : 0;
    __syncthreads();
    tmp[threadIdx.x] += t;
    __syncthreads();
  }
  if (i < n) outv[i] = tmp[threadIdx.x] - v;
  if (threadIdx.x == 255) psum[blockIdx.x] = tmp[255];
}

__global__ __launch_bounds__(1024) void scan_psum_kernel(int* __restrict__ psum, int nb) {
  __shared__ int tmp[1024];
  int i = threadIdx.x;
  int v = (i < nb) ? psum[i] : 0;
  tmp[i] = v;
  __syncthreads();
  for (int off = 1; off < 1024; off <<= 1) {
    int t = (i >= off) ? tmp[i - off] : 0;
    __syncthreads();
    tmp[i] += t;
    __syncthreads();
  }
  if (i < nb) psum[i] = tmp[i] - v;
}

__global__ void scan_add_kernel(int* __restrict__ v, const int* __restrict__ psum, int n) {
  int i = blockIdx.x * 256 + threadIdx.x;
  if (i < n) v[i] += psum[blockIdx.x];
}

// boffs[g] = scanned histG[g*NBLK]; boffs[NBall] = Etot
__global__ void extract_offs_kernel(const int* __restrict__ histG, int* __restrict__ boffs,
                                    int NBall, int Etot) {
  int i = blockIdx.x * 256 + threadIdx.x;
  if (i < NBall) boffs[i] = histG[i * NBLK];
  if (i == NBall) boffs[NBall] = Etot;
}

// ---------------- in-place csrify: bins -> per-node CSR + noffs + dinv ----------------
__global__ __launch_bounds__(256) void csrify3_kernel(
    int* __restrict__ bins, const int* __restrict__ boffs,
    int* __restrict__ no1, int* __restrict__ no2, int* __restrict__ no3,
    float* __restrict__ dv1, float* __restrict__ dv2, float* __restrict__ dv3,
    int n1, int n2, int n3, int NB) {
  __shared__ int cnt[256];
  __shared__ int scanv[256];
  __shared__ int cur[256];
  const int bb = blockIdx.x;
  const int tid = threadIdx.x;
  const int l = bb / NB;
  const int lb = bb - l * NB;
  const int npb = 32 << l;                       // 32 / 64 / 128
  const int nl = (l == 0) ? n1 : (l == 1) ? n2 : n3;
  int* noffs = (l == 0) ? no1 : (l == 1) ? no2 : no3;
  float* dinv = (l == 0) ? dv1 : (l == 1) ? dv2 : dv3;
  cnt[tid] = 0;
  __syncthreads();
  const int start = boffs[bb], end = boffs[bb + 1];
  int rv[12];  // bucket <= 3072 edges (L3 mean 2046, +22 sigma headroom)
#pragma unroll
  for (int kk = 0; kk < 12; kk++) {
    int e = start + tid + kk * 256;
    rv[kk] = (e < end) ? bins[e] : -1;
    if (rv[kk] != -1) atomicAdd(&cnt[rv[kk] >> 18], 1);
  }
  __syncthreads();
  scanv[tid] = cnt[tid];
  __syncthreads();
  for (int off = 1; off < 256; off <<= 1) {
    int t = (tid >= off) ? scanv[tid - off] : 0;
    __syncthreads();
    scanv[tid] += t;
    __syncthreads();
  }
  int excl = scanv[tid] - cnt[tid];
  cur[tid] = excl;
  int node = lb * npb + tid;
  if (tid < npb && node < nl) {
    noffs[node] = start + excl;
    dinv[node] = rsqrtf((float)cnt[tid] + 1.0f);  // +1 = self loop
  }
  if (lb == NB - 1 && tid == 0) noffs[nl] = end;
  __syncthreads();
#pragma unroll
  for (int kk = 0; kk < 12; kk++) {
    if (rv[kk] != -1) {
      int dl = rv[kk] >> 18;
      int pos = start + atomicAdd(&cur[dl], 1);
      bins[pos] = rv[kk] & 0x3FFFF;  // in-place: all reads done before first write
    }
  }
}

__global__ __launch_bounds__(256) void csrify4_kernel(int* __restrict__ bins,
                                                      const int* __restrict__ boffs,
                                                      int* __restrict__ noffs,
                                                      float* __restrict__ dinv,
                                                      int n, int NB) {
  __shared__ int cnt[256];
  __shared__ int scanv[256];
  __shared__ int cur[256];
  const int bb = blockIdx.x;
  const int tid = threadIdx.x;
  cnt[tid] = 0;
  __syncthreads();
  const int start = boffs[bb], end = boffs[bb + 1];
  int rv[24];  // bucket <= 6144 edges (mean 4092, +32 sigma headroom)
#pragma unroll
  for (int kk = 0; kk < 24; kk++) {
    int e = start + tid + kk * 256;
    rv[kk] = (e < end) ? bins[e] : -1;
    if (rv[kk] != -1) atomicAdd(&cnt[rv[kk] >> 18], 1);
  }
  __syncthreads();
  scanv[tid] = cnt[tid];
  __syncthreads();
  for (int off = 1; off < 256; off <<= 1) {
    int t = (tid >= off) ? scanv[tid - off] : 0;
    __syncthreads();
    scanv[tid] += t;
    __syncthreads();
  }
  int excl = scanv[tid] - cnt[tid];
  cur[tid] = excl;
  int node = bb * 256 + tid;
  if (node < n) {
    noffs[node] = start + excl;
    dinv[node] = rsqrtf((float)cnt[tid] + 1.0f);
  }
  if (bb == NB - 1 && tid == 0) noffs[n] = end;
  __syncthreads();
#pragma unroll
  for (int kk = 0; kk < 24; kk++) {
    if (rv[kk] != -1) {
      int dl = rv[kk] >> 18;
      int pos = start + atomicAdd(&cur[dl], 1);
      bins[pos] = rv[kk] & 0x3FFFF;
    }
  }
}

// ---------------- float4 per-node gather: 4 channels/thread, register acc ----------------
template <int C, int HSHIFT>
__global__ __launch_bounds__(256) void node_gather4_kernel(const int* __restrict__ csr,
                                                           const int* __restrict__ noffs,
                                                           const float* __restrict__ dinv,
                                                           const float* __restrict__ h,
                                                           const float* __restrict__ b,
                                                           float* __restrict__ out, int n) {
  constexpr int LPN = C / 4;        // lanes per node: 64 / 32 / 16 / 2
  constexpr int NPB = 256 / LPN;    // nodes per block: 4 / 8 / 16 / 128
  const int node = blockIdx.x * NPB + threadIdx.x / LPN;
  const int c4 = (threadIdx.x % LPN) * 4;
  if (node >= n) return;
  const float4* __restrict__ h4 = reinterpret_cast<const float4*>(h);
  const int start = noffs[node];
  const int end = noffs[node + 1];
  const float dd = dinv[node];
  float4 sv = h4[(((long)(node >> HSHIFT)) * C + c4) >> 2];  // self loop
  float4 acc;
  acc.x = dd * sv.x; acc.y = dd * sv.y; acc.z = dd * sv.z; acc.w = dd * sv.w;
  int j = start;
  for (; j + 1 < end; j += 2) {
    int s0 = csr[j], s1 = csr[j + 1];
    float w0 = dinv[s0], w1 = dinv[s1];
    float4 v0 = h4[(((long)(s0 >> HSHIFT)) * C + c4) >> 2];
    float4 v1 = h4[(((long)(s1 >> HSHIFT)) * C + c4) >> 2];
    acc.x = fmaf(w0, v0.x, acc.x); acc.y = fmaf(w0, v0.y, acc.y);
    acc.z = fmaf(w0, v0.z, acc.z); acc.w = fmaf(w0, v0.w, acc.w);
    acc.x = fmaf(w1, v1.x, acc.x); acc.y = fmaf(w1, v1.y, acc.y);
    acc.z = fmaf(w1, v1.z, acc.z); acc.w = fmaf(w1, v1.w, acc.w);
  }
  if (j < end) {
    int s0 = csr[j];
    float w0 = dinv[s0];
    float4 v0 = h4[(((long)(s0 >> HSHIFT)) * C + c4) >> 2];
    acc.x = fmaf(w0, v0.x, acc.x); acc.y = fmaf(w0, v0.y, acc.y);
    acc.z = fmaf(w0, v0.z, acc.z); acc.w = fmaf(w0, v0.w, acc.w);
  }
  const float4 bb4 = *reinterpret_cast<const float4*>(b + c4);
  float4 o;
  o.x = fmaf(dd, acc.x, bb4.x); o.y = fmaf(dd, acc.y, bb4.y);
  o.z = fmaf(dd, acc.z, bb4.z); o.w = fmaf(dd, acc.w, bb4.w);
  *reinterpret_cast<float4*>(out + (long)node * C + c4) = o;
}

// ---------------- gemm_t: transposed-LDS, b128-clean, column-split GEMM ----------------
// Block computes TM=32 rows x CT cols of h = act(x) @ W. 256 threads = (CT/4) col-groups
// x RG row-groups; thread tile = TR rows x 4 cols (one b128 ws read, one b128/b64 a read).
template <int CIN, int COUT, int CT, bool RELU>
__global__ __launch_bounds__(256) void gemm_t(const float* __restrict__ x,
                                              const float* __restrict__ W,
                                              float* __restrict__ h, int n) {
  constexpr int TM = 32, KT = 32;
  constexpr int CG = CT / 4;       // 32 (CT=128) or 16 (CT=64)
  constexpr int RG = 256 / CG;     // 8 or 16
  constexpr int TR = TM / RG;      // 4 or 2
  __shared__ float xs_t[KT][TM + 4];  // transposed x tile; +4 keeps rows 16B-aligned
  __shared__ float ws[KT][CT];
  const int tid = threadIdx.x;
  const int cg = tid % CG;
  const int rg = tid / CG;
  const int c0 = cg * 4;
  const int r0 = rg * TR;
  const int rowbase = blockIdx.x * TM;
  const int colbase = blockIdx.y * CT;
  float acc[TR][4];
#pragma unroll
  for (int i = 0; i < TR; i++)
#pragma unroll
    for (int j = 0; j < 4; j++) acc[i][j] = 0.f;

  for (int k0 = 0; k0 < CIN; k0 += KT) {
    __syncthreads();
    {  // stage x transposed: 1 float4 per thread (r = tid>>3, kq = tid&7)
      int r = tid >> 3, kq = tid & 7;
      int gr = rowbase + r;
      float4 v = make_float4(0.f, 0.f, 0.f, 0.f);
      if (gr < n) v = *reinterpret_cast<const float4*>(&x[(long)gr * CIN + k0 + kq * 4]);
      if (RELU) {
        v.x = fmaxf(v.x, 0.f); v.y = fmaxf(v.y, 0.f);
        v.z = fmaxf(v.z, 0.f); v.w = fmaxf(v.w, 0.f);
      }
      int kk = kq * 4;
      xs_t[kk][r] = v.x; xs_t[kk + 1][r] = v.y; xs_t[kk + 2][r] = v.z; xs_t[kk + 3][r] = v.w;
    }
    {  // stage W tile: KT*CT/4 float4s, coalesced
      constexpr int WF4 = KT * CG;  // float4 count
#pragma unroll
      for (int t = 0; t < WF4 / 256; t++) {
        int i4 = tid + t * 256;
        int k = i4 / CG, cq = i4 % CG;
        float4 wv = *reinterpret_cast<const float4*>(&W[(long)(k0 + k) * COUT + colbase + cq * 4]);
        *reinterpret_cast<float4*>(&ws[k][cq * 4]) = wv;
      }
    }
    __syncthreads();
#pragma unroll 8
    for (int k = 0; k < KT; k++) {
      float4 wv = *reinterpret_cast<const float4*>(&ws[k][c0]);  // lane-consecutive b128
      float a[TR];
      if (TR == 4) {
        float4 av = *reinterpret_cast<const float4*>(&xs_t[k][r0]);
        a[0] = av.x; a[1] = av.y; a[2] = av.z; a[3] = av.w;
      } else {
        float2 av = *reinterpret_cast<const float2*>(&xs_t[k][r0]);
        a[0] = av.x; a[1] = av.y;
      }
#pragma unroll
      for (int i = 0; i < TR; i++) {
        acc[i][0] = fmaf(a[i], wv.x, acc[i][0]);
        acc[i][1] = fmaf(a[i], wv.y, acc[i][1]);
        acc[i][2] = fmaf(a[i], wv.z, acc[i][2]);
        acc[i][3] = fmaf(a[i], wv.w, acc[i][3]);
      }
    }
  }
#pragma unroll
  for (int i = 0; i < TR; i++) {
    int gr = rowbase + r0 + i;
    if (gr < n) {
      float4 o = make_float4(acc[i][0], acc[i][1], acc[i][2], acc[i][3]);
      *reinterpret_cast<float4*>(&h[(long)gr * COUT + colbase + c0]) = o;
    }
  }
}

// small-COUT GEMM (layer 4, COUT=8) — unchanged
template <int CIN, int COUT, int TM, bool RELU>
__global__ __launch_bounds__(256) void gemm_small(const float* __restrict__ x,
                                                  const float* __restrict__ W,
                                                  float* __restrict__ h, int n) {
  __shared__ float xs[TM][CIN + 1];
  const int tid = threadIdx.x;
  const int base = blockIdx.x * TM;
  for (int idx = tid; idx < TM * CIN; idx += 256) {
    int m = idx / CIN, k = idx - m * CIN;
    int r = base + m;
    float v = 0.f;
    if (r < n) {
      v = x[(long)r * CIN + k];
      if (RELU) v = fmaxf(v, 0.f);
    }
    xs[m][k] = v;
  }
  __syncthreads();
  constexpr int GROUPS = 256 / COUT;
  constexpr int ACC = TM / GROUPS;
  const int c = tid % COUT;
  const int mg = tid / COUT;
  float acc[ACC];
#pragma unroll
  for (int a = 0; a < ACC; a++) acc[a] = 0.f;
#pragma unroll 8
  for (int k = 0; k < CIN; k++) {
    float wk = W[k * COUT + c];
#pragma unroll
    for (int a = 0; a < ACC; a++) acc[a] = fmaf(xs[mg + a * GROUPS][k], wk, acc[a]);
  }
#pragma unroll
  for (int a = 0; a < ACC; a++) {
    int r = base + mg + a * GROUPS;
    if (r < n) h[(long)r * COUT + c] = acc[a];
  }
}

extern "C" void kernel_launch(void* const* d_in, const int* in_sizes, int n_in,
                              void* d_out, int out_size, void* d_ws, size_t ws_size,
                              hipStream_t stream) {
  const float* z  = (const float*)d_in[0];
  const int* ei   = (const int*)d_in[1];
  const int* ps2  = (const int*)d_in[2];
  const int* ps1  = (const int*)d_in[3];
  const int* ps0  = (const int*)d_in[4];
  const float* W1 = (const float*)d_in[5];  const float* b1 = (const float*)d_in[6];
  const float* W2 = (const float*)d_in[7];  const float* b2 = (const float*)d_in[8];
  const float* W3 = (const float*)d_in[9];  const float* b3 = (const float*)d_in[10];
  const float* W4 = (const float*)d_in[11]; const float* b4 = (const float*)d_in[12];
  float* out = (float*)d_out;

  const int N  = in_sizes[0] / 256;  // 25000
  const int E1 = in_sizes[1] / 2;    // 400000
  const int E2 = in_sizes[2] / 2;    // 800000
  const int E3 = in_sizes[3] / 2;    // 1600000
  const int E4 = in_sizes[4] / 2;    // 3200000
  const int n1 = N, n2 = 2 * N, n3 = 4 * N, n4 = 8 * N;
  const int E12 = E1 + E2, ETA = E1 + E2 + E3;  // combined L1-3 edge space
  const int NB = cdiv(n1, 32);       // 782 buckets/layer (NPB = 32<<l keeps NB constant)
  const int NB3 = 3 * NB;
  const int NTA = NB3 * NBLK;        // 600,576
  const int nbsA = cdiv(NTA, 256);   // 2347
  const int nbsA2 = cdiv(nbsA, 256); // 10
  const int NTB = NB * NBLK;         // 200,704
  const int nbsB = cdiv(NTB, 256);   // 784

  // ---- workspace map (identical to R8, proven) ----
  float* F = (float*)d_ws;
  float* h1 = F;                 // 25.6 MB
  float* out1 = F + 6400000;     // 25.6 MB
  float* h2 = F;                 // 12.8 MB
  int* binsB = (int*)(F + 3200000);  // csr4, 12.8 MB (overlays dead h1 upper half)
  float* out2 = F + 6400000;
  float* h3 = F;
  float* out3 = F + 6400000;
  float* h4 = F;

  int* P = (int*)(F + 12800000);
  int* binsA = P;                         // ETA ints (csr123 after in-place csrify)
  int* no1 = P + ETA;
  int* no2 = no1 + (n1 + 1);
  int* no3 = no2 + (n2 + 1);
  int* no4 = no3 + (n3 + 1);
  float* dv1 = (float*)(no4 + (n4 + 1));
  float* dv2 = dv1 + n1;
  float* dv3 = dv2 + n2;
  float* dv4 = dv3 + n3;
  int* S = (int*)(dv4 + n4);
  int* histA = S;                         // NTA
  int* psumA = histA + NTA;               // 3200
  int* psumB = psumA + 3200;              // 64
  int* boffsA = psumB + 64;               // NB3+1
  int* histB = boffsA + (NB3 + 1);        // NTB
  int* psumC = histB + NTB;               // 1024
  int* boffsB = psumC + 1024;             // NB+1

  // ---------------- partition layers 1-3 (one batched chain) ----------------
  {
    int chunk = cdiv(ETA, NBLK);
    part_hist3_kernel<<<NBLK, 256, 0, stream>>>(ei + E1, ps2 + E2, ps1 + E3, histA,
                                                E1, E12, ETA, chunk, NB);
    scan_block_kernel<<<nbsA, 256, 0, stream>>>(histA, histA, psumA, NTA);
    scan_block_kernel<<<nbsA2, 256, 0, stream>>>(psumA, psumA, psumB, nbsA);
    scan_psum_kernel<<<1, 1024, 0, stream>>>(psumB, nbsA2);
    scan_add_kernel<<<nbsA2, 256, 0, stream>>>(psumA, psumB, nbsA);
    scan_add_kernel<<<nbsA, 256, 0, stream>>>(histA, psumA, NTA);
    extract_offs_kernel<<<cdiv(NB3 + 1, 256), 256, 0, stream>>>(histA, boffsA, NB3, ETA);
    part_scatter3_kernel<<<NBLK, 256, 0, stream>>>(ei, ei + E1, ps2, ps2 + E2, ps1, ps1 + E3,
                                                   histA, binsA, E1, E12, ETA, chunk, NB);
    csrify3_kernel<<<NB3, 256, 0, stream>>>(binsA, boffsA, no1, no2, no3,
                                            dv1, dv2, dv3, n1, n2, n3, NB);
  }
  // layer-4 hist+scan upfront (touches only S region)
  {
    int chunk4 = cdiv(E4, NBLK);
    part_hist4_kernel<<<NBLK, 256, 0, stream>>>(ps0 + E4, histB, E4, chunk4, NB);
    scan_block_kernel<<<nbsB, 256, 0, stream>>>(histB, histB, psumC, NTB);
    scan_psum_kernel<<<1, 1024, 0, stream>>>(psumC, nbsB);
    scan_add_kernel<<<nbsB, 256, 0, stream>>>(histB, psumC, NTB);
    extract_offs_kernel<<<cdiv(NB + 1, 256), 256, 0, stream>>>(histB, boffsB, NB, E4);
  }

  // ---------------- Layer 1: h1 (Nx256), out1 ----------------
  gemm_t<256, 256, 128, false><<<dim3(cdiv(n1, 32), 2), 256, 0, stream>>>(z, W1, h1, n1);
  node_gather4_kernel<256, 0><<<cdiv(n1, 4), 256, 0, stream>>>(binsA, no1, dv1, h1, b1, out1, n1);

  // layer-4 scatter+csrify (binsB overlays dead h1 upper half; after gather1)
  {
    int chunk4 = cdiv(E4, NBLK);
    part_scatter4_kernel<<<NBLK, 256, 0, stream>>>(ps0, ps0 + E4, histB, binsB, E4, chunk4, NB);
    csrify4_kernel<<<NB, 256, 0, stream>>>(binsB, boffsB, no4, dv4, n4, NB);
  }

  // ---------------- Layer 2: h2 (Nx128), out2 (2N x 128) ----------------
  gemm_t<256, 128, 64, true><<<dim3(cdiv(N, 32), 2), 256, 0, stream>>>(out1, W2, h2, N);
  node_gather4_kernel<128, 1><<<cdiv(n2, 8), 256, 0, stream>>>(binsA, no2, dv2, h2, b2, out2, n2);

  // ---------------- Layer 3: h3 (2N x 64), out3 (4N x 64) ----------------
  gemm_t<128, 64, 64, true><<<dim3(cdiv(2 * N, 32), 1), 256, 0, stream>>>(out2, W3, h3, 2 * N);
  node_gather4_kernel<64, 1><<<cdiv(n3, 16), 256, 0, stream>>>(binsA, no3, dv3, h3, b3, out3, n3);

  // ---------------- Layer 4: h4 (4N x 8), out4 = d_out (8N x 8) ----------------
  gemm_small<64, 8, 32, true><<<cdiv(4 * N, 32), 256, 0, stream>>>(out3, W4, h4, 4 * N);
  node_gather4_kernel<8, 1><<<cdiv(n4, 128), 256, 0, stream>>>(binsB, no4, dv4, h4, b4, out, n4);
}

// Round 10
// 637.475 us; speedup vs baseline: 8.4421x; 1.0971x over previous
//
#include <hip/hip_runtime.h>

// GCN decoder: batched deterministic radix partition (LDS-staged scatter) ->
// in-place per-node CSR -> float4 register gather; gemm_t fp32 GEMMs.
// upsample2 identity: h = upsample2(x) @ W has h[2i]==h[2i+1] -> compute h on the
// pre-upsample node set, index with (node >> HSHIFT).
// out[d][c] = b[c] + dinv[d]*( dinv[d]*h[d>>s][c] + sum_{e:dst=d} dinv[src]*h[src>>s][c] )
// R9 post-mortem: part_scatter4 72us with 4-5x write amplification (4B scattered stores,
// partial-sector evictions) + 1 block/CU. R10: scatter stages its whole chunk in LDS and
// flushes per-bucket segments contiguously; uniform 256-node buckets (shift 8) for all
// layers -> ~16-entry (64B) flush segments, unified csrify, smaller hist/scan tables.

static inline int cdiv(long a, int b) { return (int)((a + b - 1) / b); }
static constexpr int NBLK = 256;  // partition chunks / histogram columns

// ---------------- hist: per-chunk histogram (bucket-major table), 1024 threads ----------------
__global__ __launch_bounds__(1024) void part_hist3_kernel(
    const int* __restrict__ d1, const int* __restrict__ d2, const int* __restrict__ d3,
    int* __restrict__ histG, int E1, int E12, int ET, int chunk, int NBall, int B2, int B3) {
  __shared__ int hist[688];
  for (int i = threadIdx.x; i < NBall; i += 1024) hist[i] = 0;
  __syncthreads();
  const int k = blockIdx.x;
  const int lo = k * chunk, hi = min(ET, lo + chunk);
  for (int e = lo + (int)threadIdx.x; e < hi; e += 1024) {
    int l, ee;
    if (e < E1) { l = 0; ee = e; }
    else if (e < E12) { l = 1; ee = e - E1; }
    else { l = 2; ee = e - E12; }
    const int* dp = (l == 0) ? d1 : (l == 1) ? d2 : d3;
    int base = (l == 0) ? 0 : (l == 1) ? B2 : B3;
    atomicAdd(&hist[base + (dp[ee] >> 8)], 1);
  }
  __syncthreads();
  for (int i = threadIdx.x; i < NBall; i += 1024) histG[i * NBLK + k] = hist[i];
}

__global__ __launch_bounds__(1024) void part_hist4_kernel(const int* __restrict__ dst,
                                                          int* __restrict__ histG,
                                                          int E, int chunk, int NBall) {
  __shared__ int hist[784];
  for (int i = threadIdx.x; i < NBall; i += 1024) hist[i] = 0;
  __syncthreads();
  const int k = blockIdx.x;
  const int lo = k * chunk, hi = min(E, lo + chunk);
  for (int e = lo + (int)threadIdx.x; e < hi; e += 1024)
    atomicAdd(&hist[dst[e] >> 8], 1);
  __syncthreads();
  for (int i = threadIdx.x; i < NBall; i += 1024) histG[i * NBLK + k] = hist[i];
}

// ---------------- 3-kernel scan primitives (in-place safe) ----------------
__global__ void scan_block_kernel(const int* __restrict__ in, int* __restrict__ outv,
                                  int* __restrict__ psum, int n) {
  __shared__ int tmp[256];
  int i = blockIdx.x * 256 + threadIdx.x;
  int v = (i < n) ? in[i] : 0;
  tmp[threadIdx.x] = v;
  __syncthreads();
  for (int off = 1; off < 256; off <<= 1) {
    int t = (threadIdx.x >= off) ? tmp[threadIdx.x - off] : 0;
    __syncthreads();
    tmp[threadIdx.x] += t;
    __syncthreads();
  }
  if (i < n) outv[i] = tmp[threadIdx.x] - v;
  if (threadIdx.x == 255) psum[blockIdx.x] = tmp[255];
}

__global__ __launch_bounds__(1024) void scan_psum_kernel(int* __restrict__ psum, int nb) {
  __shared__ int tmp[1024];
  int i = threadIdx.x;
  int v = (i < nb) ? psum[i] : 0;
  tmp[i] = v;
  __syncthreads();
  for (int off = 1; off < 1024; off <<= 1) {
    int t = (i >= off) ? tmp[i - off] : 0;
    __syncthreads();
    tmp[i] += t;
    __syncthreads();
  }
  if (i < nb) psum[i] = tmp[i] - v;
}

__global__ void scan_add_kernel(int* __restrict__ v, const int* __restrict__ psum, int n) {
  int i = blockIdx.x * 256 + threadIdx.x;
  if (i < n) v[i] += psum[blockIdx.x];
}

// boffs[g] = scanned histG[g*NBLK]; boffs[NBall] = Etot
__global__ void extract_offs_kernel(const int* __restrict__ histG, int* __restrict__ boffs,
                                    int NBall, int Etot) {
  int i = blockIdx.x * 256 + threadIdx.x;
  if (i < NBall) boffs[i] = histG[i * NBLK];
  if (i == NBall) boffs[NBall] = Etot;
}

// ---------------- LDS-staged scatter: stage chunk locally, flush contiguous segments ----------
template <int CHUNK, int NBCAP>
__global__ __launch_bounds__(512) void part_scatter3_staged(
    const int* __restrict__ s1, const int* __restrict__ d1,
    const int* __restrict__ s2, const int* __restrict__ d2,
    const int* __restrict__ s3, const int* __restrict__ d3,
    const int* __restrict__ histG, int* __restrict__ bins,
    int E1, int E12, int ET, int chunk, int NBall, int B2, int B3) {
  __shared__ int stage[CHUNK];
  __shared__ int cnt[NBCAP];
  __shared__ int cur[NBCAP];
  const int tid = threadIdx.x;
  const int k = blockIdx.x;
  for (int i = tid; i < NBall; i += 512) cnt[i] = 0;
  __syncthreads();
  const int lo = k * chunk, hi = min(ET, lo + chunk);
  // pass 1: local histogram (dst only)
  for (int e = lo + tid; e < hi; e += 512) {
    int l, ee;
    if (e < E1) { l = 0; ee = e; }
    else if (e < E12) { l = 1; ee = e - E1; }
    else { l = 2; ee = e - E12; }
    const int* dp = (l == 0) ? d1 : (l == 1) ? d2 : d3;
    int base = (l == 0) ? 0 : (l == 1) ? B2 : B3;
    atomicAdd(&cnt[base + (dp[ee] >> 8)], 1);
  }
  __syncthreads();
  // strip-scan cnt -> cur (exclusive); strip sums scratch in stage[0..511] (free pre-pass2)
  constexpr int STR = (NBCAP + 511) / 512;
  const int st0 = tid * STR;
  const int st1 = min(st0 + STR, NBall);
  int sum = 0;
  for (int i = st0; i < st1; i++) sum += cnt[i];
  stage[tid] = sum;
  __syncthreads();
  for (int off = 1; off < 512; off <<= 1) {
    int t = (tid >= off) ? stage[tid - off] : 0;
    __syncthreads();
    stage[tid] += t;
    __syncthreads();
  }
  int run = stage[tid] - sum;  // exclusive base of this strip
  __syncthreads();             // all strip-sum reads done before stage reuse
  for (int i = st0; i < st1; i++) { cur[i] = run; run += cnt[i]; }
  __syncthreads();
  // pass 2: stage packed entries at block-local positions
  for (int e = lo + tid; e < hi; e += 512) {
    int l, ee;
    if (e < E1) { l = 0; ee = e; }
    else if (e < E12) { l = 1; ee = e - E1; }
    else { l = 2; ee = e - E12; }
    const int* sp = (l == 0) ? s1 : (l == 1) ? s2 : s3;
    const int* dp = (l == 0) ? d1 : (l == 1) ? d2 : d3;
    int base = (l == 0) ? 0 : (l == 1) ? B2 : B3;
    int d = dp[ee];
    int p = atomicAdd(&cur[base + (d >> 8)], 1);  // LDS atomic, block-local position
    stage[p] = sp[ee] | ((d & 255) << 18);
  }
  __syncthreads();
  // flush: wave-per-bucket round-robin; each segment contiguous in LDS and global
  const int wave = tid >> 6, lane = tid & 63;
  for (int b = wave; b < NBall; b += 8) {
    int cb = cnt[b];
    int lbase = cur[b] - cb;
    int gbase = histG[b * NBLK + k];
    for (int t = lane; t < cb; t += 64) bins[gbase + t] = stage[lbase + t];
  }
}

template <int CHUNK, int NBCAP>
__global__ __launch_bounds__(512) void part_scatter4_staged(
    const int* __restrict__ src, const int* __restrict__ dst,
    const int* __restrict__ histG, int* __restrict__ bins,
    int E, int chunk, int NBall) {
  __shared__ int stage[CHUNK];
  __shared__ int cnt[NBCAP];
  __shared__ int cur[NBCAP];
  const int tid = threadIdx.x;
  const int k = blockIdx.x;
  for (int i = tid; i < NBall; i += 512) cnt[i] = 0;
  __syncthreads();
  const int lo = k * chunk, hi = min(E, lo + chunk);
  for (int e = lo + tid; e < hi; e += 512) atomicAdd(&cnt[dst[e] >> 8], 1);
  __syncthreads();
  constexpr int STR = (NBCAP + 511) / 512;
  const int st0 = tid * STR;
  const int st1 = min(st0 + STR, NBall);
  int sum = 0;
  for (int i = st0; i < st1; i++) sum += cnt[i];
  stage[tid] = sum;
  __syncthreads();
  for (int off = 1; off < 512; off <<= 1) {
    int t = (tid >= off) ? stage[tid - off] : 0;
    __syncthreads();
    stage[tid] += t;
    __syncthreads();
  }
  int run = stage[tid] - sum;
  __syncthreads();
  for (int i = st0; i < st1; i++) { cur[i] = run; run += cnt[i]; }
  __syncthreads();
  for (int e = lo + tid; e < hi; e += 512) {
    int d = dst[e];
    int p = atomicAdd(&cur[d >> 8], 1);
    stage[p] = src[e] | ((d & 255) << 18);
  }
  __syncthreads();
  const int wave = tid >> 6, lane = tid & 63;
  for (int b = wave; b < NBall; b += 8) {
    int cb = cnt[b];
    int lbase = cur[b] - cb;
    int gbase = histG[b * NBLK + k];
    for (int t = lane; t < cb; t += 64) bins[gbase + t] = stage[lbase + t];
  }
}

// ---------------- in-place csrify (uniform 256-node buckets, rv[24]) ----------------
__global__ __launch_bounds__(256) void csrifyA_kernel(
    int* __restrict__ bins, const int* __restrict__ boffs,
    int* __restrict__ no1, int* __restrict__ no2, int* __restrict__ no3,
    float* __restrict__ dv1, float* __restrict__ dv2, float* __restrict__ dv3,
    int n1, int n2, int n3, int NB1, int NB2, int NB3) {
  __shared__ int cnt[256];
  __shared__ int scanv[256];
  __shared__ int cur[256];
  const int bb = blockIdx.x;
  const int tid = threadIdx.x;
  int lb, nl, nbl;
  int* noffs;
  float* dinv;
  if (bb < NB1) { lb = bb; nl = n1; nbl = NB1; noffs = no1; dinv = dv1; }
  else if (bb < NB1 + NB2) { lb = bb - NB1; nl = n2; nbl = NB2; noffs = no2; dinv = dv2; }
  else { lb = bb - NB1 - NB2; nl = n3; nbl = NB3; noffs = no3; dinv = dv3; }
  cnt[tid] = 0;
  __syncthreads();
  const int start = boffs[bb], end = boffs[bb + 1];
  int rv[24];  // bucket <= 6144 edges (mean ~4082, +32 sigma headroom)
#pragma unroll
  for (int kk = 0; kk < 24; kk++) {
    int e = start + tid + kk * 256;
    rv[kk] = (e < end) ? bins[e] : -1;
    if (rv[kk] != -1) atomicAdd(&cnt[rv[kk] >> 18], 1);
  }
  __syncthreads();
  scanv[tid] = cnt[tid];
  __syncthreads();
  for (int off = 1; off < 256; off <<= 1) {
    int t = (tid >= off) ? scanv[tid - off] : 0;
    __syncthreads();
    scanv[tid] += t;
    __syncthreads();
  }
  int excl = scanv[tid] - cnt[tid];
  cur[tid] = excl;
  int node = lb * 256 + tid;
  if (node < nl) {
    noffs[node] = start + excl;
    dinv[node] = rsqrtf((float)cnt[tid] + 1.0f);  // +1 = self loop
  }
  if (lb == nbl - 1 && tid == 0) noffs[nl] = end;
  __syncthreads();
#pragma unroll
  for (int kk = 0; kk < 24; kk++) {
    if (rv[kk] != -1) {
      int dl = rv[kk] >> 18;
      int pos = start + atomicAdd(&cur[dl], 1);
      bins[pos] = rv[kk] & 0x3FFFF;  // in-place: all reads done before first write
    }
  }
}

__global__ __launch_bounds__(256) void csrify4_kernel(int* __restrict__ bins,
                                                      const int* __restrict__ boffs,
                                                      int* __restrict__ noffs,
                                                      float* __restrict__ dinv,
                                                      int n, int NB) {
  __shared__ int cnt[256];
  __shared__ int scanv[256];
  __shared__ int cur[256];
  const int bb = blockIdx.x;
  const int tid = threadIdx.x;
  cnt[tid] = 0;
  __syncthreads();
  const int start = boffs[bb], end = boffs[bb + 1];
  int rv[24];
#pragma unroll
  for (int kk = 0; kk < 24; kk++) {
    int e = start + tid + kk * 256;
    rv[kk] = (e < end) ? bins[e] : -1;
    if (rv[kk] != -1) atomicAdd(&cnt[rv[kk] >> 18], 1);
  }
  __syncthreads();
  scanv[tid] = cnt[tid];
  __syncthreads();
  for (int off = 1; off < 256; off <<= 1) {
    int t = (tid >= off) ? scanv[tid - off] : 0;
    __syncthreads();
    scanv[tid] += t;
    __syncthreads();
  }
  int excl = scanv[tid] - cnt[tid];
  cur[tid] = excl;
  int node = bb * 256 + tid;
  if (node < n) {
    noffs[node] = start + excl;
    dinv[node] = rsqrtf((float)cnt[tid] + 1.0f);
  }
  if (bb == NB - 1 && tid == 0) noffs[n] = end;
  __syncthreads();
#pragma unroll
  for (int kk = 0; kk < 24; kk++) {
    if (rv[kk] != -1) {
      int dl = rv[kk] >> 18;
      int pos = start + atomicAdd(&cur[dl], 1);
      bins[pos] = rv[kk] & 0x3FFFF;
    }
  }
}

// ---------------- float4 per-node gather (unchanged, proven) ----------------
template <int C, int HSHIFT>
__global__ __launch_bounds__(256) void node_gather4_kernel(const int* __restrict__ csr,
                                                           const int* __restrict__ noffs,
                                                           const float* __restrict__ dinv,
                                                           const float* __restrict__ h,
                                                           const float* __restrict__ b,
                                                           float* __restrict__ out, int n) {
  constexpr int LPN = C / 4;
  constexpr int NPB = 256 / LPN;
  const int node = blockIdx.x * NPB + threadIdx.x / LPN;
  const int c4 = (threadIdx.x % LPN) * 4;
  if (node >= n) return;
  const float4* __restrict__ h4 = reinterpret_cast<const float4*>(h);
  const int start = noffs[node];
  const int end = noffs[node + 1];
  const float dd = dinv[node];
  float4 sv = h4[(((long)(node >> HSHIFT)) * C + c4) >> 2];  // self loop
  float4 acc;
  acc.x = dd * sv.x; acc.y = dd * sv.y; acc.z = dd * sv.z; acc.w = dd * sv.w;
  int j = start;
  for (; j + 1 < end; j += 2) {
    int s0 = csr[j], s1 = csr[j + 1];
    float w0 = dinv[s0], w1 = dinv[s1];
    float4 v0 = h4[(((long)(s0 >> HSHIFT)) * C + c4) >> 2];
    float4 v1 = h4[(((long)(s1 >> HSHIFT)) * C + c4) >> 2];
    acc.x = fmaf(w0, v0.x, acc.x); acc.y = fmaf(w0, v0.y, acc.y);
    acc.z = fmaf(w0, v0.z, acc.z); acc.w = fmaf(w0, v0.w, acc.w);
    acc.x = fmaf(w1, v1.x, acc.x); acc.y = fmaf(w1, v1.y, acc.y);
    acc.z = fmaf(w1, v1.z, acc.z); acc.w = fmaf(w1, v1.w, acc.w);
  }
  if (j < end) {
    int s0 = csr[j];
    float w0 = dinv[s0];
    float4 v0 = h4[(((long)(s0 >> HSHIFT)) * C + c4) >> 2];
    acc.x = fmaf(w0, v0.x, acc.x); acc.y = fmaf(w0, v0.y, acc.y);
    acc.z = fmaf(w0, v0.z, acc.z); acc.w = fmaf(w0, v0.w, acc.w);
  }
  const float4 bb4 = *reinterpret_cast<const float4*>(b + c4);
  float4 o;
  o.x = fmaf(dd, acc.x, bb4.x); o.y = fmaf(dd, acc.y, bb4.y);
  o.z = fmaf(dd, acc.z, bb4.z); o.w = fmaf(dd, acc.w, bb4.w);
  *reinterpret_cast<float4*>(out + (long)node * C + c4) = o;
}

// ---------------- gemm_t (unchanged, proven R9) ----------------
template <int CIN, int COUT, int CT, bool RELU>
__global__ __launch_bounds__(256) void gemm_t(const float* __restrict__ x,
                                              const float* __restrict__ W,
                                              float* __restrict__ h, int n) {
  constexpr int TM = 32, KT = 32;
  constexpr int CG = CT / 4;
  constexpr int RG = 256 / CG;
  constexpr int TR = TM / RG;
  __shared__ float xs_t[KT][TM + 4];
  __shared__ float ws[KT][CT];
  const int tid = threadIdx.x;
  const int cg = tid % CG;
  const int rg = tid / CG;
  const int c0 = cg * 4;
  const int r0 = rg * TR;
  const int rowbase = blockIdx.x * TM;
  const int colbase = blockIdx.y * CT;
  float acc[TR][4];
#pragma unroll
  for (int i = 0; i < TR; i++)
#pragma unroll
    for (int j = 0; j < 4; j++) acc[i][j] = 0.f;

  for (int k0 = 0; k0 < CIN; k0 += KT) {
    __syncthreads();
    {
      int r = tid >> 3, kq = tid & 7;
      int gr = rowbase + r;
      float4 v = make_float4(0.f, 0.f, 0.f, 0.f);
      if (gr < n) v = *reinterpret_cast<const float4*>(&x[(long)gr * CIN + k0 + kq * 4]);
      if (RELU) {
        v.x = fmaxf(v.x, 0.f); v.y = fmaxf(v.y, 0.f);
        v.z = fmaxf(v.z, 0.f); v.w = fmaxf(v.w, 0.f);
      }
      int kk = kq * 4;
      xs_t[kk][r] = v.x; xs_t[kk + 1][r] = v.y; xs_t[kk + 2][r] = v.z; xs_t[kk + 3][r] = v.w;
    }
    {
      constexpr int WF4 = KT * CG;
#pragma unroll
      for (int t = 0; t < WF4 / 256; t++) {
        int i4 = tid + t * 256;
        int k = i4 / CG, cq = i4 % CG;
        float4 wv = *reinterpret_cast<const float4*>(&W[(long)(k0 + k) * COUT + colbase + cq * 4]);
        *reinterpret_cast<float4*>(&ws[k][cq * 4]) = wv;
      }
    }
    __syncthreads();
#pragma unroll 8
    for (int k = 0; k < KT; k++) {
      float4 wv = *reinterpret_cast<const float4*>(&ws[k][c0]);
      float a[TR];
      if (TR == 4) {
        float4 av = *reinterpret_cast<const float4*>(&xs_t[k][r0]);
        a[0] = av.x; a[1] = av.y; a[2] = av.z; a[3] = av.w;
      } else {
        float2 av = *reinterpret_cast<const float2*>(&xs_t[k][r0]);
        a[0] = av.x; a[1] = av.y;
      }
#pragma unroll
      for (int i = 0; i < TR; i++) {
        acc[i][0] = fmaf(a[i], wv.x, acc[i][0]);
        acc[i][1] = fmaf(a[i], wv.y, acc[i][1]);
        acc[i][2] = fmaf(a[i], wv.z, acc[i][2]);
        acc[i][3] = fmaf(a[i], wv.w, acc[i][3]);
      }
    }
  }
#pragma unroll
  for (int i = 0; i < TR; i++) {
    int gr = rowbase + r0 + i;
    if (gr < n) {
      float4 o = make_float4(acc[i][0], acc[i][1], acc[i][2], acc[i][3]);
      *reinterpret_cast<float4*>(&h[(long)gr * COUT + colbase + c0]) = o;
    }
  }
}

template <int CIN, int COUT, int TM, bool RELU>
__global__ __launch_bounds__(256) void gemm_small(const float* __restrict__ x,
                                                  const float* __restrict__ W,
                                                  float* __restrict__ h, int n) {
  __shared__ float xs[TM][CIN + 1];
  const int tid = threadIdx.x;
  const int base = blockIdx.x * TM;
  for (int idx = tid; idx < TM * CIN; idx += 256) {
    int m = idx / CIN, k = idx - m * CIN;
    int r = base + m;
    float v = 0.f;
    if (r < n) {
      v = x[(long)r * CIN + k];
      if (RELU) v = fmaxf(v, 0.f);
    }
    xs[m][k] = v;
  }
  __syncthreads();
  constexpr int GROUPS = 256 / COUT;
  constexpr int ACC = TM / GROUPS;
  const int c = tid % COUT;
  const int mg = tid / COUT;
  float acc[ACC];
#pragma unroll
  for (int a = 0; a < ACC; a++) acc[a] = 0.f;
#pragma unroll 8
  for (int k = 0; k < CIN; k++) {
    float wk = W[k * COUT + c];
#pragma unroll
    for (int a = 0; a < ACC; a++) acc[a] = fmaf(xs[mg + a * GROUPS][k], wk, acc[a]);
  }
#pragma unroll
  for (int a = 0; a < ACC; a++) {
    int r = base + mg + a * GROUPS;
    if (r < n) h[(long)r * COUT + c] = acc[a];
  }
}

extern "C" void kernel_launch(void* const* d_in, const int* in_sizes, int n_in,
                              void* d_out, int out_size, void* d_ws, size_t ws_size,
                              hipStream_t stream) {
  const float* z  = (const float*)d_in[0];
  const int* ei   = (const int*)d_in[1];
  const int* ps2  = (const int*)d_in[2];
  const int* ps1  = (const int*)d_in[3];
  const int* ps0  = (const int*)d_in[4];
  const float* W1 = (const float*)d_in[5];  const float* b1 = (const float*)d_in[6];
  const float* W2 = (const float*)d_in[7];  const float* b2 = (const float*)d_in[8];
  const float* W3 = (const float*)d_in[9];  const float* b3 = (const float*)d_in[10];
  const float* W4 = (const float*)d_in[11]; const float* b4 = (const float*)d_in[12];
  float* out = (float*)d_out;

  const int N  = in_sizes[0] / 256;  // 25000
  const int E1 = in_sizes[1] / 2;    // 400000
  const int E2 = in_sizes[2] / 2;    // 800000
  const int E3 = in_sizes[3] / 2;    // 1600000
  const int E4 = in_sizes[4] / 2;    // 3200000
  const int n1 = N, n2 = 2 * N, n3 = 4 * N, n4 = 8 * N;
  const int E12 = E1 + E2, ETA = E1 + E2 + E3;
  // uniform 256-node buckets
  const int NB1 = cdiv(n1, 256);     // 98
  const int NB2 = cdiv(n2, 256);     // 196
  const int NB3 = cdiv(n3, 256);     // 391
  const int NB4 = cdiv(n4, 256);     // 782
  const int NBA = NB1 + NB2 + NB3;   // 685
  const int B2b = NB1, B3b = NB1 + NB2;
  const int NTA = NBA * NBLK;        // 175,360
  const int nbsA = cdiv(NTA, 256);   // 685  (<= 1024 -> simple scan)
  const int NTB = NB4 * NBLK;        // 200,192
  const int nbsB = cdiv(NTB, 256);   // 782
  const int chunk3 = cdiv(ETA, NBLK);  // 10,938
  const int chunk4 = cdiv(E4, NBLK);   // 12,500

  // ---- workspace map (same F-region scheme as R8/R9, proven) ----
  float* F = (float*)d_ws;
  float* h1 = F;
  float* out1 = F + 6400000;
  float* h2 = F;
  int* binsB = (int*)(F + 3200000);  // csr4; overlays dead h1 upper half (post-gather1)
  float* out2 = F + 6400000;
  float* h3 = F;
  float* out3 = F + 6400000;
  float* h4 = F;

  int* P = (int*)(F + 12800000);
  int* binsA = P;                         // ETA ints (csr123 after in-place csrify)
  int* no1 = P + ETA;
  int* no2 = no1 + (n1 + 1);
  int* no3 = no2 + (n2 + 1);
  int* no4 = no3 + (n3 + 1);
  float* dv1 = (float*)(no4 + (n4 + 1));
  float* dv2 = dv1 + n1;
  float* dv3 = dv2 + n2;
  float* dv4 = dv3 + n3;
  int* S = (int*)(dv4 + n4);
  int* histA = S;                         // NTA
  int* psumA = histA + NTA;               // 1024
  int* boffsA = psumA + 1024;             // NBA+1
  int* histB = boffsA + (NBA + 1);        // NTB
  int* psumC = histB + NTB;               // 1024
  int* boffsB = psumC + 1024;             // NB4+1

  // ---------------- partition layers 1-3 (batched chain, staged scatter) ----------------
  part_hist3_kernel<<<NBLK, 1024, 0, stream>>>(ei + E1, ps2 + E2, ps1 + E3, histA,
                                               E1, E12, ETA, chunk3, NBA, B2b, B3b);
  scan_block_kernel<<<nbsA, 256, 0, stream>>>(histA, histA, psumA, NTA);
  scan_psum_kernel<<<1, 1024, 0, stream>>>(psumA, nbsA);
  scan_add_kernel<<<nbsA, 256, 0, stream>>>(histA, psumA, NTA);
  extract_offs_kernel<<<cdiv(NBA + 1, 256), 256, 0, stream>>>(histA, boffsA, NBA, ETA);
  part_scatter3_staged<10944, 688><<<NBLK, 512, 0, stream>>>(
      ei, ei + E1, ps2, ps2 + E2, ps1, ps1 + E3, histA, binsA,
      E1, E12, ETA, chunk3, NBA, B2b, B3b);
  csrifyA_kernel<<<NBA, 256, 0, stream>>>(binsA, boffsA, no1, no2, no3,
                                          dv1, dv2, dv3, n1, n2, n3, NB1, NB2, NB3);

  // layer-4 hist+scan upfront (touches only S region)
  part_hist4_kernel<<<NBLK, 1024, 0, stream>>>(ps0 + E4, histB, E4, chunk4, NB4);
  scan_block_kernel<<<nbsB, 256, 0, stream>>>(histB, histB, psumC, NTB);
  scan_psum_kernel<<<1, 1024, 0, stream>>>(psumC, nbsB);
  scan_add_kernel<<<nbsB, 256, 0, stream>>>(histB, psumC, NTB);
  extract_offs_kernel<<<cdiv(NB4 + 1, 256), 256, 0, stream>>>(histB, boffsB, NB4, E4);

  // ---------------- Layer 1: h1 (Nx256), out1 ----------------
  gemm_t<256, 256, 128, false><<<dim3(cdiv(n1, 32), 2), 256, 0, stream>>>(z, W1, h1, n1);
  node_gather4_kernel<256, 0><<<cdiv(n1, 4), 256, 0, stream>>>(binsA, no1, dv1, h1, b1, out1, n1);

  // layer-4 scatter+csrify (binsB overlays dead h1 upper half; after gather1)
  part_scatter4_staged<12512, 784><<<NBLK, 512, 0, stream>>>(ps0, ps0 + E4, histB, binsB,
                                                             E4, chunk4, NB4);
  csrify4_kernel<<<NB4, 256, 0, stream>>>(binsB, boffsB, no4, dv4, n4, NB4);

  // ---------------- Layer 2: h2 (Nx128), out2 (2N x 128) ----------------
  gemm_t<256, 128, 64, true><<<dim3(cdiv(N, 32), 2), 256, 0, stream>>>(out1, W2, h2, N);
  node_gather4_kernel<128, 1><<<cdiv(n2, 8), 256, 0, stream>>>(binsA, no2, dv2, h2, b2, out2, n2);

  // ---------------- Layer 3: h3 (2N x 64), out3 (4N x 64) ----------------
  gemm_t<128, 64, 64, true><<<dim3(cdiv(2 * N, 32), 1), 256, 0, stream>>>(out2, W3, h3, 2 * N);
  node_gather4_kernel<64, 1><<<cdiv(n3, 16), 256, 0, stream>>>(binsA, no3, dv3, h3, b3, out3, n3);

  // ---------------- Layer 4: h4 (4N x 8), out4 = d_out (8N x 8) ----------------
  gemm_small<64, 8, 32, true><<<cdiv(4 * N, 32), 256, 0, stream>>>(out3, W4, h4, 4 * N);
  node_gather4_kernel<8, 1><<<cdiv(n4, 128), 256, 0, stream>>>(binsB, no4, dv4, h4, b4, out, n4);
}

// Round 11
// 599.210 us; speedup vs baseline: 8.9812x; 1.0639x over previous
//
#include <hip/hip_runtime.h>

// GCN decoder: batched deterministic radix partition (LDS-staged scatter, 512x1024) ->
// in-place per-node CSR -> float4 register gather; gemm_t fp32 GEMMs.
// upsample2 identity: h = upsample2(x) @ W has h[2i]==h[2i+1] -> compute h on the
// pre-upsample node set, index with (node >> HSHIFT).
// out[d][c] = b[c] + dinv[d]*( dinv[d]*h[d>>s][c] + sum_{e:dst=d} dinv[src]*h[src>>s][c] )
// R10 post-mortem: staged scatter killed write-amp (WRITE 64->18 MB) but is occupancy-bound:
// 256 blocks = 1 block/CU, 8 waves (18.7% occ), 0.78 TB/s effective. R11: NBLK=512 chunks,
// 1024-thread scatter blocks (31 KB LDS -> 2 blocks/CU = 32 waves), two-level psum scans.

static inline int cdiv(long a, int b) { return (int)((a + b - 1) / b); }
static constexpr int NBLK = 512;  // partition chunks / histogram columns

// ---------------- hist: per-chunk histogram (bucket-major table) ----------------
__global__ __launch_bounds__(1024) void part_hist3_kernel(
    const int* __restrict__ d1, const int* __restrict__ d2, const int* __restrict__ d3,
    int* __restrict__ histG, int E1, int E12, int ET, int chunk, int NBall, int B2, int B3) {
  __shared__ int hist[688];
  for (int i = threadIdx.x; i < NBall; i += 1024) hist[i] = 0;
  __syncthreads();
  const int k = blockIdx.x;
  const int lo = k * chunk, hi = min(ET, lo + chunk);
  for (int e = lo + (int)threadIdx.x; e < hi; e += 1024) {
    int l, ee;
    if (e < E1) { l = 0; ee = e; }
    else if (e < E12) { l = 1; ee = e - E1; }
    else { l = 2; ee = e - E12; }
    const int* dp = (l == 0) ? d1 : (l == 1) ? d2 : d3;
    int base = (l == 0) ? 0 : (l == 1) ? B2 : B3;
    atomicAdd(&hist[base + (dp[ee] >> 8)], 1);
  }
  __syncthreads();
  for (int i = threadIdx.x; i < NBall; i += 1024) histG[i * NBLK + k] = hist[i];
}

__global__ __launch_bounds__(1024) void part_hist4_kernel(const int* __restrict__ dst,
                                                          int* __restrict__ histG,
                                                          int E, int chunk, int NBall) {
  __shared__ int hist[784];
  for (int i = threadIdx.x; i < NBall; i += 1024) hist[i] = 0;
  __syncthreads();
  const int k = blockIdx.x;
  const int lo = k * chunk, hi = min(E, lo + chunk);
  for (int e = lo + (int)threadIdx.x; e < hi; e += 1024)
    atomicAdd(&hist[dst[e] >> 8], 1);
  __syncthreads();
  for (int i = threadIdx.x; i < NBall; i += 1024) histG[i * NBLK + k] = hist[i];
}

// ---------------- scan primitives (in-place safe) ----------------
__global__ void scan_block_kernel(const int* __restrict__ in, int* __restrict__ outv,
                                  int* __restrict__ psum, int n) {
  __shared__ int tmp[256];
  int i = blockIdx.x * 256 + threadIdx.x;
  int v = (i < n) ? in[i] : 0;
  tmp[threadIdx.x] = v;
  __syncthreads();
  for (int off = 1; off < 256; off <<= 1) {
    int t = (threadIdx.x >= off) ? tmp[threadIdx.x - off] : 0;
    __syncthreads();
    tmp[threadIdx.x] += t;
    __syncthreads();
  }
  if (i < n) outv[i] = tmp[threadIdx.x] - v;
  if (threadIdx.x == 255) psum[blockIdx.x] = tmp[255];
}

__global__ __launch_bounds__(1024) void scan_psum_kernel(int* __restrict__ psum, int nb) {
  __shared__ int tmp[1024];
  int i = threadIdx.x;
  int v = (i < nb) ? psum[i] : 0;
  tmp[i] = v;
  __syncthreads();
  for (int off = 1; off < 1024; off <<= 1) {
    int t = (i >= off) ? tmp[i - off] : 0;
    __syncthreads();
    tmp[i] += t;
    __syncthreads();
  }
  if (i < nb) psum[i] = tmp[i] - v;
}

__global__ void scan_add_kernel(int* __restrict__ v, const int* __restrict__ psum, int n) {
  int i = blockIdx.x * 256 + threadIdx.x;
  if (i < n) v[i] += psum[blockIdx.x];
}

// boffs[g] = scanned histG[g*NBLK]; boffs[NBall] = Etot
__global__ void extract_offs_kernel(const int* __restrict__ histG, int* __restrict__ boffs,
                                    int NBall, int Etot) {
  int i = blockIdx.x * 256 + threadIdx.x;
  if (i < NBall) boffs[i] = histG[i * NBLK];
  if (i == NBall) boffs[NBall] = Etot;
}

// ---------------- LDS-staged scatter (1024 threads): stage chunk, flush contiguous ----------
template <int CHUNK, int NBCAP>
__global__ __launch_bounds__(1024) void part_scatter3_staged(
    const int* __restrict__ s1, const int* __restrict__ d1,
    const int* __restrict__ s2, const int* __restrict__ d2,
    const int* __restrict__ s3, const int* __restrict__ d3,
    const int* __restrict__ histG, int* __restrict__ bins,
    int E1, int E12, int ET, int chunk, int NBall, int B2, int B3) {
  __shared__ int stage[CHUNK];
  __shared__ int cnt[NBCAP];
  __shared__ int cur[NBCAP];
  const int tid = threadIdx.x;
  const int k = blockIdx.x;
  for (int i = tid; i < NBall; i += 1024) cnt[i] = 0;
  __syncthreads();
  const int lo = k * chunk, hi = min(ET, lo + chunk);
  // pass 1: local histogram (dst only)
  for (int e = lo + tid; e < hi; e += 1024) {
    int l, ee;
    if (e < E1) { l = 0; ee = e; }
    else if (e < E12) { l = 1; ee = e - E1; }
    else { l = 2; ee = e - E12; }
    const int* dp = (l == 0) ? d1 : (l == 1) ? d2 : d3;
    int base = (l == 0) ? 0 : (l == 1) ? B2 : B3;
    atomicAdd(&cnt[base + (dp[ee] >> 8)], 1);
  }
  __syncthreads();
  // scan cnt -> cur (exclusive): one bucket per thread (NBCAP <= 1024), scratch in stage[]
  int sum = (tid < NBall) ? cnt[tid] : 0;
  stage[tid] = sum;
  __syncthreads();
  for (int off = 1; off < 1024; off <<= 1) {
    int t = (tid >= off) ? stage[tid - off] : 0;
    __syncthreads();
    stage[tid] += t;
    __syncthreads();
  }
  if (tid < NBall) cur[tid] = stage[tid] - sum;
  __syncthreads();  // stage reads done before pass-2 reuse
  // pass 2: stage packed entries at block-local positions
  for (int e = lo + tid; e < hi; e += 1024) {
    int l, ee;
    if (e < E1) { l = 0; ee = e; }
    else if (e < E12) { l = 1; ee = e - E1; }
    else { l = 2; ee = e - E12; }
    const int* sp = (l == 0) ? s1 : (l == 1) ? s2 : s3;
    const int* dp = (l == 0) ? d1 : (l == 1) ? d2 : d3;
    int base = (l == 0) ? 0 : (l == 1) ? B2 : B3;
    int d = dp[ee];
    int p = atomicAdd(&cur[base + (d >> 8)], 1);  // LDS atomic, block-local position
    stage[p] = sp[ee] | ((d & 255) << 18);
  }
  __syncthreads();
  // flush: wave-per-bucket round-robin; each segment contiguous in LDS and global
  const int wave = tid >> 6, lane = tid & 63;
  for (int b = wave; b < NBall; b += 16) {
    int cb = cnt[b];
    int lbase = cur[b] - cb;
    int gbase = histG[b * NBLK + k];
    for (int t = lane; t < cb; t += 64) bins[gbase + t] = stage[lbase + t];
  }
}

template <int CHUNK, int NBCAP>
__global__ __launch_bounds__(1024) void part_scatter4_staged(
    const int* __restrict__ src, const int* __restrict__ dst,
    const int* __restrict__ histG, int* __restrict__ bins,
    int E, int chunk, int NBall) {
  __shared__ int stage[CHUNK];
  __shared__ int cnt[NBCAP];
  __shared__ int cur[NBCAP];
  const int tid = threadIdx.x;
  const int k = blockIdx.x;
  for (int i = tid; i < NBall; i += 1024) cnt[i] = 0;
  __syncthreads();
  const int lo = k * chunk, hi = min(E, lo + chunk);
  for (int e = lo + tid; e < hi; e += 1024) atomicAdd(&cnt[dst[e] >> 8], 1);
  __syncthreads();
  int sum = (tid < NBall) ? cnt[tid] : 0;
  stage[tid] = sum;
  __syncthreads();
  for (int off = 1; off < 1024; off <<= 1) {
    int t = (tid >= off) ? stage[tid - off] : 0;
    __syncthreads();
    stage[tid] += t;
    __syncthreads();
  }
  if (tid < NBall) cur[tid] = stage[tid] - sum;
  __syncthreads();
  for (int e = lo + tid; e < hi; e += 1024) {
    int d = dst[e];
    int p = atomicAdd(&cur[d >> 8], 1);
    stage[p] = src[e] | ((d & 255) << 18);
  }
  __syncthreads();
  const int wave = tid >> 6, lane = tid & 63;
  for (int b = wave; b < NBall; b += 16) {
    int cb = cnt[b];
    int lbase = cur[b] - cb;
    int gbase = histG[b * NBLK + k];
    for (int t = lane; t < cb; t += 64) bins[gbase + t] = stage[lbase + t];
  }
}

// ---------------- in-place csrify (uniform 256-node buckets, rv[24]) ----------------
__global__ __launch_bounds__(256) void csrifyA_kernel(
    int* __restrict__ bins, const int* __restrict__ boffs,
    int* __restrict__ no1, int* __restrict__ no2, int* __restrict__ no3,
    float* __restrict__ dv1, float* __restrict__ dv2, float* __restrict__ dv3,
    int n1, int n2, int n3, int NB1, int NB2, int NB3) {
  __shared__ int cnt[256];
  __shared__ int scanv[256];
  __shared__ int cur[256];
  const int bb = blockIdx.x;
  const int tid = threadIdx.x;
  int lb, nl, nbl;
  int* noffs;
  float* dinv;
  if (bb < NB1) { lb = bb; nl = n1; nbl = NB1; noffs = no1; dinv = dv1; }
  else if (bb < NB1 + NB2) { lb = bb - NB1; nl = n2; nbl = NB2; noffs = no2; dinv = dv2; }
  else { lb = bb - NB1 - NB2; nl = n3; nbl = NB3; noffs = no3; dinv = dv3; }
  cnt[tid] = 0;
  __syncthreads();
  const int start = boffs[bb], end = boffs[bb + 1];
  int rv[24];  // bucket <= 6144 edges (mean ~4082, +32 sigma headroom)
#pragma unroll
  for (int kk = 0; kk < 24; kk++) {
    int e = start + tid + kk * 256;
    rv[kk] = (e < end) ? bins[e] : -1;
    if (rv[kk] != -1) atomicAdd(&cnt[rv[kk] >> 18], 1);
  }
  __syncthreads();
  scanv[tid] = cnt[tid];
  __syncthreads();
  for (int off = 1; off < 256; off <<= 1) {
    int t = (tid >= off) ? scanv[tid - off] : 0;
    __syncthreads();
    scanv[tid] += t;
    __syncthreads();
  }
  int excl = scanv[tid] - cnt[tid];
  cur[tid] = excl;
  int node = lb * 256 + tid;
  if (node < nl) {
    noffs[node] = start + excl;
    dinv[node] = rsqrtf((float)cnt[tid] + 1.0f);  // +1 = self loop
  }
  if (lb == nbl - 1 && tid == 0) noffs[nl] = end;
  __syncthreads();
#pragma unroll
  for (int kk = 0; kk < 24; kk++) {
    if (rv[kk] != -1) {
      int dl = rv[kk] >> 18;
      int pos = start + atomicAdd(&cur[dl], 1);
      bins[pos] = rv[kk] & 0x3FFFF;  // in-place: all reads done before first write
    }
  }
}

__global__ __launch_bounds__(256) void csrify4_kernel(int* __restrict__ bins,
                                                      const int* __restrict__ boffs,
                                                      int* __restrict__ noffs,
                                                      float* __restrict__ dinv,
                                                      int n, int NB) {
  __shared__ int cnt[256];
  __shared__ int scanv[256];
  __shared__ int cur[256];
  const int bb = blockIdx.x;
  const int tid = threadIdx.x;
  cnt[tid] = 0;
  __syncthreads();
  const int start = boffs[bb], end = boffs[bb + 1];
  int rv[24];
#pragma unroll
  for (int kk = 0; kk < 24; kk++) {
    int e = start + tid + kk * 256;
    rv[kk] = (e < end) ? bins[e] : -1;
    if (rv[kk] != -1) atomicAdd(&cnt[rv[kk] >> 18], 1);
  }
  __syncthreads();
  scanv[tid] = cnt[tid];
  __syncthreads();
  for (int off = 1; off < 256; off <<= 1) {
    int t = (tid >= off) ? scanv[tid - off] : 0;
    __syncthreads();
    scanv[tid] += t;
    __syncthreads();
  }
  int excl = scanv[tid] - cnt[tid];
  cur[tid] = excl;
  int node = bb * 256 + tid;
  if (node < n) {
    noffs[node] = start + excl;
    dinv[node] = rsqrtf((float)cnt[tid] + 1.0f);
  }
  if (bb == NB - 1 && tid == 0) noffs[n] = end;
  __syncthreads();
#pragma unroll
  for (int kk = 0; kk < 24; kk++) {
    if (rv[kk] != -1) {
      int dl = rv[kk] >> 18;
      int pos = start + atomicAdd(&cur[dl], 1);
      bins[pos] = rv[kk] & 0x3FFFF;
    }
  }
}

// ---------------- float4 per-node gather (unchanged, proven) ----------------
template <int C, int HSHIFT>
__global__ __launch_bounds__(256) void node_gather4_kernel(const int* __restrict__ csr,
                                                           const int* __restrict__ noffs,
                                                           const float* __restrict__ dinv,
                                                           const float* __restrict__ h,
                                                           const float* __restrict__ b,
                                                           float* __restrict__ out, int n) {
  constexpr int LPN = C / 4;
  constexpr int NPB = 256 / LPN;
  const int node = blockIdx.x * NPB + threadIdx.x / LPN;
  const int c4 = (threadIdx.x % LPN) * 4;
  if (node >= n) return;
  const float4* __restrict__ h4 = reinterpret_cast<const float4*>(h);
  const int start = noffs[node];
  const int end = noffs[node + 1];
  const float dd = dinv[node];
  float4 sv = h4[(((long)(node >> HSHIFT)) * C + c4) >> 2];  // self loop
  float4 acc;
  acc.x = dd * sv.x; acc.y = dd * sv.y; acc.z = dd * sv.z; acc.w = dd * sv.w;
  int j = start;
  for (; j + 1 < end; j += 2) {
    int s0 = csr[j], s1 = csr[j + 1];
    float w0 = dinv[s0], w1 = dinv[s1];
    float4 v0 = h4[(((long)(s0 >> HSHIFT)) * C + c4) >> 2];
    float4 v1 = h4[(((long)(s1 >> HSHIFT)) * C + c4) >> 2];
    acc.x = fmaf(w0, v0.x, acc.x); acc.y = fmaf(w0, v0.y, acc.y);
    acc.z = fmaf(w0, v0.z, acc.z); acc.w = fmaf(w0, v0.w, acc.w);
    acc.x = fmaf(w1, v1.x, acc.x); acc.y = fmaf(w1, v1.y, acc.y);
    acc.z = fmaf(w1, v1.z, acc.z); acc.w = fmaf(w1, v1.w, acc.w);
  }
  if (j < end) {
    int s0 = csr[j];
    float w0 = dinv[s0];
    float4 v0 = h4[(((long)(s0 >> HSHIFT)) * C + c4) >> 2];
    acc.x = fmaf(w0, v0.x, acc.x); acc.y = fmaf(w0, v0.y, acc.y);
    acc.z = fmaf(w0, v0.z, acc.z); acc.w = fmaf(w0, v0.w, acc.w);
  }
  const float4 bb4 = *reinterpret_cast<const float4*>(b + c4);
  float4 o;
  o.x = fmaf(dd, acc.x, bb4.x); o.y = fmaf(dd, acc.y, bb4.y);
  o.z = fmaf(dd, acc.z, bb4.z); o.w = fmaf(dd, acc.w, bb4.w);
  *reinterpret_cast<float4*>(out + (long)node * C + c4) = o;
}

// ---------------- gemm_t (unchanged, proven R9) ----------------
template <int CIN, int COUT, int CT, bool RELU>
__global__ __launch_bounds__(256) void gemm_t(const float* __restrict__ x,
                                              const float* __restrict__ W,
                                              float* __restrict__ h, int n) {
  constexpr int TM = 32, KT = 32;
  constexpr int CG = CT / 4;
  constexpr int RG = 256 / CG;
  constexpr int TR = TM / RG;
  __shared__ float xs_t[KT][TM + 4];
  __shared__ float ws[KT][CT];
  const int tid = threadIdx.x;
  const int cg = tid % CG;
  const int rg = tid / CG;
  const int c0 = cg * 4;
  const int r0 = rg * TR;
  const int rowbase = blockIdx.x * TM;
  const int colbase = blockIdx.y * CT;
  float acc[TR][4];
#pragma unroll
  for (int i = 0; i < TR; i++)
#pragma unroll
    for (int j = 0; j < 4; j++) acc[i][j] = 0.f;

  for (int k0 = 0; k0 < CIN; k0 += KT) {
    __syncthreads();
    {
      int r = tid >> 3, kq = tid & 7;
      int gr = rowbase + r;
      float4 v = make_float4(0.f, 0.f, 0.f, 0.f);
      if (gr < n) v = *reinterpret_cast<const float4*>(&x[(long)gr * CIN + k0 + kq * 4]);
      if (RELU) {
        v.x = fmaxf(v.x, 0.f); v.y = fmaxf(v.y, 0.f);
        v.z = fmaxf(v.z, 0.f); v.w = fmaxf(v.w, 0.f);
      }
      int kk = kq * 4;
      xs_t[kk][r] = v.x; xs_t[kk + 1][r] = v.y; xs_t[kk + 2][r] = v.z; xs_t[kk + 3][r] = v.w;
    }
    {
      constexpr int WF4 = KT * CG;
#pragma unroll
      for (int t = 0; t < WF4 / 256; t++) {
        int i4 = tid + t * 256;
        int k = i4 / CG, cq = i4 % CG;
        float4 wv = *reinterpret_cast<const float4*>(&W[(long)(k0 + k) * COUT + colbase + cq * 4]);
        *reinterpret_cast<float4*>(&ws[k][cq * 4]) = wv;
      }
    }
    __syncthreads();
#pragma unroll 8
    for (int k = 0; k < KT; k++) {
      float4 wv = *reinterpret_cast<const float4*>(&ws[k][c0]);
      float a[TR];
      if (TR == 4) {
        float4 av = *reinterpret_cast<const float4*>(&xs_t[k][r0]);
        a[0] = av.x; a[1] = av.y; a[2] = av.z; a[3] = av.w;
      } else {
        float2 av = *reinterpret_cast<const float2*>(&xs_t[k][r0]);
        a[0] = av.x; a[1] = av.y;
      }
#pragma unroll
      for (int i = 0; i < TR; i++) {
        acc[i][0] = fmaf(a[i], wv.x, acc[i][0]);
        acc[i][1] = fmaf(a[i], wv.y, acc[i][1]);
        acc[i][2] = fmaf(a[i], wv.z, acc[i][2]);
        acc[i][3] = fmaf(a[i], wv.w, acc[i][3]);
      }
    }
  }
#pragma unroll
  for (int i = 0; i < TR; i++) {
    int gr = rowbase + r0 + i;
    if (gr < n) {
      float4 o = make_float4(acc[i][0], acc[i][1], acc[i][2], acc[i][3]);
      *reinterpret_cast<float4*>(&h[(long)gr * COUT + colbase + c0]) = o;
    }
  }
}

template <int CIN, int COUT, int TM, bool RELU>
__global__ __launch_bounds__(256) void gemm_small(const float* __restrict__ x,
                                                  const float* __restrict__ W,
                                                  float* __restrict__ h, int n) {
  __shared__ float xs[TM][CIN + 1];
  const int tid = threadIdx.x;
  const int base = blockIdx.x * TM;
  for (int idx = tid; idx < TM * CIN; idx += 256) {
    int m = idx / CIN, k = idx - m * CIN;
    int r = base + m;
    float v = 0.f;
    if (r < n) {
      v = x[(long)r * CIN + k];
      if (RELU) v = fmaxf(v, 0.f);
    }
    xs[m][k] = v;
  }
  __syncthreads();
  constexpr int GROUPS = 256 / COUT;
  constexpr int ACC = TM / GROUPS;
  const int c = tid % COUT;
  const int mg = tid / COUT;
  float acc[ACC];
#pragma unroll
  for (int a = 0; a < ACC; a++) acc[a] = 0.f;
#pragma unroll 8
  for (int k = 0; k < CIN; k++) {
    float wk = W[k * COUT + c];
#pragma unroll
    for (int a = 0; a < ACC; a++) acc[a] = fmaf(xs[mg + a * GROUPS][k], wk, acc[a]);
  }
#pragma unroll
  for (int a = 0; a < ACC; a++) {
    int r = base + mg + a * GROUPS;
    if (r < n) h[(long)r * COUT + c] = acc[a];
  }
}

extern "C" void kernel_launch(void* const* d_in, const int* in_sizes, int n_in,
                              void* d_out, int out_size, void* d_ws, size_t ws_size,
                              hipStream_t stream) {
  const float* z  = (const float*)d_in[0];
  const int* ei   = (const int*)d_in[1];
  const int* ps2  = (const int*)d_in[2];
  const int* ps1  = (const int*)d_in[3];
  const int* ps0  = (const int*)d_in[4];
  const float* W1 = (const float*)d_in[5];  const float* b1 = (const float*)d_in[6];
  const float* W2 = (const float*)d_in[7];  const float* b2 = (const float*)d_in[8];
  const float* W3 = (const float*)d_in[9];  const float* b3 = (const float*)d_in[10];
  const float* W4 = (const float*)d_in[11]; const float* b4 = (const float*)d_in[12];
  float* out = (float*)d_out;

  const int N  = in_sizes[0] / 256;  // 25000
  const int E1 = in_sizes[1] / 2;    // 400000
  const int E2 = in_sizes[2] / 2;    // 800000
  const int E3 = in_sizes[3] / 2;    // 1600000
  const int E4 = in_sizes[4] / 2;    // 3200000
  const int n1 = N, n2 = 2 * N, n3 = 4 * N, n4 = 8 * N;
  const int E12 = E1 + E2, ETA = E1 + E2 + E3;
  // uniform 256-node buckets
  const int NB1 = cdiv(n1, 256);     // 98
  const int NB2 = cdiv(n2, 256);     // 196
  const int NB3 = cdiv(n3, 256);     // 391
  const int NB4 = cdiv(n4, 256);     // 782
  const int NBA = NB1 + NB2 + NB3;   // 685
  const int B2b = NB1, B3b = NB1 + NB2;
  const int NTA = NBA * NBLK;        // 350,720
  const int nbsA = cdiv(NTA, 256);   // 1370
  const int nbsA2 = cdiv(nbsA, 256); // 6
  const int NTB = NB4 * NBLK;        // 400,384
  const int nbsB = cdiv(NTB, 256);   // 1564
  const int nbsB2 = cdiv(nbsB, 256); // 7
  const int chunk3 = cdiv(ETA, NBLK);  // 5469
  const int chunk4 = cdiv(E4, NBLK);   // 6250

  // ---- workspace map (same F-region scheme as R8-R10, proven) ----
  float* F = (float*)d_ws;
  float* h1 = F;
  float* out1 = F + 6400000;
  float* h2 = F;
  int* binsB = (int*)(F + 3200000);  // csr4; overlays dead h1 upper half (post-gather1)
  float* out2 = F + 6400000;
  float* h3 = F;
  float* out3 = F + 6400000;
  float* h4 = F;

  int* P = (int*)(F + 12800000);
  int* binsA = P;                         // ETA ints (csr123 after in-place csrify)
  int* no1 = P + ETA;
  int* no2 = no1 + (n1 + 1);
  int* no3 = no2 + (n2 + 1);
  int* no4 = no3 + (n3 + 1);
  float* dv1 = (float*)(no4 + (n4 + 1));
  float* dv2 = dv1 + n1;
  float* dv3 = dv2 + n2;
  float* dv4 = dv3 + n3;
  int* S = (int*)(dv4 + n4);
  int* histA = S;                         // NTA
  int* psumA = histA + NTA;               // 2048 (need nbsA=1370)
  int* psumA2 = psumA + 2048;             // 64
  int* boffsA = psumA2 + 64;              // NBA+1
  int* histB = boffsA + (NBA + 1);        // NTB
  int* psumB = histB + NTB;               // 2048 (need nbsB=1564)
  int* psumB2 = psumB + 2048;             // 64
  int* boffsB = psumB2 + 64;              // NB4+1

  // ---------------- partition layers 1-3 (batched chain, staged scatter) ----------------
  part_hist3_kernel<<<NBLK, 1024, 0, stream>>>(ei + E1, ps2 + E2, ps1 + E3, histA,
                                               E1, E12, ETA, chunk3, NBA, B2b, B3b);
  scan_block_kernel<<<nbsA, 256, 0, stream>>>(histA, histA, psumA, NTA);
  scan_block_kernel<<<nbsA2, 256, 0, stream>>>(psumA, psumA, psumA2, nbsA);
  scan_psum_kernel<<<1, 1024, 0, stream>>>(psumA2, nbsA2);
  scan_add_kernel<<<nbsA2, 256, 0, stream>>>(psumA, psumA2, nbsA);
  scan_add_kernel<<<nbsA, 256, 0, stream>>>(histA, psumA, NTA);
  extract_offs_kernel<<<cdiv(NBA + 1, 256), 256, 0, stream>>>(histA, boffsA, NBA, ETA);
  part_scatter3_staged<5472, 688><<<NBLK, 1024, 0, stream>>>(
      ei, ei + E1, ps2, ps2 + E2, ps1, ps1 + E3, histA, binsA,
      E1, E12, ETA, chunk3, NBA, B2b, B3b);
  csrifyA_kernel<<<NBA, 256, 0, stream>>>(binsA, boffsA, no1, no2, no3,
                                          dv1, dv2, dv3, n1, n2, n3, NB1, NB2, NB3);

  // layer-4 hist+scan upfront (touches only S region)
  part_hist4_kernel<<<NBLK, 1024, 0, stream>>>(ps0 + E4, histB, E4, chunk4, NB4);
  scan_block_kernel<<<nbsB, 256, 0, stream>>>(histB, histB, psumB, NTB);
  scan_block_kernel<<<nbsB2, 256, 0, stream>>>(psumB, psumB, psumB2, nbsB);
  scan_psum_kernel<<<1, 1024, 0, stream>>>(psumB2, nbsB2);
  scan_add_kernel<<<nbsB2, 256, 0, stream>>>(psumB, psumB2, nbsB);
  scan_add_kernel<<<nbsB, 256, 0, stream>>>(histB, psumB, NTB);
  extract_offs_kernel<<<cdiv(NB4 + 1, 256), 256, 0, stream>>>(histB, boffsB, NB4, E4);

  // ---------------- Layer 1: h1 (Nx256), out1 ----------------
  gemm_t<256, 256, 128, false><<<dim3(cdiv(n1, 32), 2), 256, 0, stream>>>(z, W1, h1, n1);
  node_gather4_kernel<256, 0><<<cdiv(n1, 4), 256, 0, stream>>>(binsA, no1, dv1, h1, b1, out1, n1);

  // layer-4 scatter+csrify (binsB overlays dead h1 upper half; after gather1)
  part_scatter4_staged<6256, 784><<<NBLK, 1024, 0, stream>>>(ps0, ps0 + E4, histB, binsB,
                                                             E4, chunk4, NB4);
  csrify4_kernel<<<NB4, 256, 0, stream>>>(binsB, boffsB, no4, dv4, n4, NB4);

  // ---------------- Layer 2: h2 (Nx128), out2 (2N x 128) ----------------
  gemm_t<256, 128, 64, true><<<dim3(cdiv(N, 32), 2), 256, 0, stream>>>(out1, W2, h2, N);
  node_gather4_kernel<128, 1><<<cdiv(n2, 8), 256, 0, stream>>>(binsA, no2, dv2, h2, b2, out2, n2);

  // ---------------- Layer 3: h3 (2N x 64), out3 (4N x 64) ----------------
  gemm_t<128, 64, 64, true><<<dim3(cdiv(2 * N, 32), 1), 256, 0, stream>>>(out2, W3, h3, 2 * N);
  node_gather4_kernel<64, 1><<<cdiv(n3, 16), 256, 0, stream>>>(binsA, no3, dv3, h3, b3, out3, n3);

  // ---------------- Layer 4: h4 (4N x 8), out4 = d_out (8N x 8) ----------------
  gemm_small<64, 8, 32, true><<<cdiv(4 * N, 32), 256, 0, stream>>>(out3, W4, h4, 4 * N);
  node_gather4_kernel<8, 1><<<cdiv(n4, 128), 256, 0, stream>>>(binsB, no4, dv4, h4, b4, out, n4);
}